// Round 1
// baseline (6965.154 us; speedup 1.0000x reference)
//
#include <hip/hip_runtime.h>

// TLOB tiny transformer, fully fused. One wave (64 lanes) per batch element.
// Lane = channel d (0..63). h[32] rows in registers per lane (column layout).
// Matmuls: activations broadcast from per-wave LDS buffer, weights transposed
// into shared LDS tile (re-staged per stage, block-wide).

constexpr int Bsz = 32768, S = 32, F = 10, D = 64, Ln = 2, DFF = 128;
constexpr int XPITCH = 68;   // floats per activation row (272B, 16B-aligned)
constexpr int WPITCH = 66;   // transposed weight pitch (2-way bank alias = free)
constexpr int NB = 4;        // batch elements per block (one per wave)

__device__ __forceinline__ float redadd16(float v) {
  v += __shfl_xor(v, 1);  v += __shfl_xor(v, 2);
  v += __shfl_xor(v, 4);  v += __shfl_xor(v, 8);
  return v;
}
__device__ __forceinline__ float redadd64(float v) {
  v += __shfl_xor(v, 1);  v += __shfl_xor(v, 2);  v += __shfl_xor(v, 4);
  v += __shfl_xor(v, 8);  v += __shfl_xor(v, 16); v += __shfl_xor(v, 32);
  return v;
}

// Transpose-stage a 64x64 weight chunk (row-major, given row stride) into
// Wt[d*WPITCH + k]. 256 threads, 16 iters, coalesced reads, 2-way LDS writes.
__device__ __forceinline__ void stageW(float* Wt, const float* __restrict__ src,
                                       int rowStride, int tid) {
  #pragma unroll
  for (int it = 0; it < 16; ++it) {
    int idx = tid + it * 256;
    int k = idx >> 6, d = idx & 63;
    Wt[d * WPITCH + k] = src[k * rowStride + d];
  }
}

// acc[s] += sum_k xb[s][k] * W[k][lane]  (K=64). xb reads are wave-broadcast.
__device__ __forceinline__ void mm64(const float* xb, const float* Wt,
                                     int lane, float* acc) {
  #pragma unroll 1
  for (int kb = 0; kb < 16; ++kb) {
    float2 wa = *(const float2*)&Wt[lane * WPITCH + kb * 4];
    float2 wb = *(const float2*)&Wt[lane * WPITCH + kb * 4 + 2];
    #pragma unroll
    for (int s = 0; s < S; ++s) {
      float4 hv = *(const float4*)&xb[s * XPITCH + kb * 4];
      acc[s] = fmaf(hv.x, wa.x, acc[s]);
      acc[s] = fmaf(hv.y, wa.y, acc[s]);
      acc[s] = fmaf(hv.z, wb.x, acc[s]);
      acc[s] = fmaf(hv.w, wb.y, acc[s]);
    }
  }
}

// LN over d (cross-lane), write result to xb; optionally keep in regs.
template <bool KEEP>
__device__ __forceinline__ void layernorm(const float* h, float* xb, int lane,
                                          float gv, float bv, float* hnreg) {
  #pragma unroll
  for (int s = 0; s < S; ++s) {
    float v = h[s];
    float sum = redadd64(v);
    float sq  = redadd64(v * v);
    float mu  = sum * (1.f / 64.f);
    float var = sq * (1.f / 64.f) - mu * mu;
    float rs  = rsqrtf(var + 1e-5f);
    float hn  = (v - mu) * rs * gv + bv;
    xb[s * XPITCH + lane] = hn;
    if (KEEP) hnreg[s] = hn;
  }
}

__global__ __launch_bounds__(256, 2)
void tlob_kernel(const float* __restrict__ x,   const float* __restrict__ w_in,
                 const float* __restrict__ b_in, const float* __restrict__ pos,
                 const float* __restrict__ wq,  const float* __restrict__ wk,
                 const float* __restrict__ wvw, const float* __restrict__ wo,
                 const float* __restrict__ bo,  const float* __restrict__ g1,
                 const float* __restrict__ be1, const float* __restrict__ g2,
                 const float* __restrict__ be2, const float* __restrict__ w1,
                 const float* __restrict__ b1,  const float* __restrict__ w2,
                 const float* __restrict__ b2,  const float* __restrict__ hw1,
                 const float* __restrict__ hb1, const float* __restrict__ hw2,
                 const float* __restrict__ hb2, float* __restrict__ out) {
  __shared__ __align__(16) float Wt[64 * WPITCH];
  __shared__ __align__(16) float xball[NB][S * XPITCH];

  const int tid  = threadIdx.x;
  const int lane = tid & 63;
  const int wid  = tid >> 6;
  const int elem = blockIdx.x * NB + wid;
  float* xb = xball[wid];

  // ---- input: x[elem] -> xb rows [s][f] ----
  {
    const float* xe = x + (size_t)elem * (S * F);
    #pragma unroll
    for (int i = 0; i < 5; ++i) {
      int idx = lane * 5 + i;
      float v = xe[idx];
      xb[(idx / 10) * XPITCH + (idx % 10)] = v;
    }
  }

  float h[S];
  {
    float wreg[F];
    #pragma unroll
    for (int f = 0; f < F; ++f) wreg[f] = w_in[f * D + lane];
    float bv = b_in[lane];
    #pragma unroll
    for (int s = 0; s < S; ++s) {
      float acc = bv + pos[s * D + lane];
      #pragma unroll
      for (int f = 0; f < F; ++f) acc = fmaf(xb[s * XPITCH + f], wreg[f], acc);
      h[s] = acc;
    }
  }

  #pragma unroll 1
  for (int layer = 0; layer < Ln; ++layer) {
    const int wofs = layer * D * D;
    float g1v = g1[layer * D + lane], be1v = be1[layer * D + lane];

    // ---- LN1 -> xb (hn) ----
    layernorm<false>(h, xb, lane, g1v, be1v, nullptr);

    // ---- k, v, q projections ----
    float kreg[S], vreg[S];
    __syncthreads();
    stageW(Wt, wk + wofs, D, tid);
    __syncthreads();
    #pragma unroll
    for (int s = 0; s < S; ++s) kreg[s] = 0.f;
    mm64(xb, Wt, lane, kreg);

    __syncthreads();
    stageW(Wt, wvw + wofs, D, tid);
    __syncthreads();
    #pragma unroll
    for (int s = 0; s < S; ++s) vreg[s] = 0.f;
    mm64(xb, Wt, lane, vreg);

    __syncthreads();
    stageW(Wt, wq + wofs, D, tid);
    __syncthreads();
    {
      float qacc[S];
      #pragma unroll
      for (int s = 0; s < S; ++s) qacc[s] = 0.f;
      mm64(xb, Wt, lane, qacc);
      #pragma unroll
      for (int s = 0; s < S; ++s) xb[s * XPITCH + lane] = qacc[s];  // hn dead
    }

    // ---- attention: per query row, 4 heads via 16-lane groups ----
    #pragma unroll 1
    for (int i = 0; i < S; ++i) {
      float qi = xb[i * XPITCH + lane];
      float sc[S];
      #pragma unroll
      for (int j = 0; j < S; ++j) {
        float p = qi * kreg[j];
        sc[j] = redadd16(p) * 0.25f;   // 1/sqrt(HD=16)
      }
      float m = sc[0];
      #pragma unroll
      for (int j = 1; j < S; ++j) m = fmaxf(m, sc[j]);
      float sum = 0.f, c = 0.f;
      #pragma unroll
      for (int j = 0; j < S; ++j) {
        float e = exp2f((sc[j] - m) * 1.4426950408889634f);
        sum += e;
        c = fmaf(e, vreg[j], c);
      }
      xb[i * XPITCH + lane] = c / sum;   // ctx row overwrites q row
    }

    // ---- output projection + residual ----
    __syncthreads();
    stageW(Wt, wo + wofs, D, tid);
    __syncthreads();
    {
      float acc[S];
      #pragma unroll
      for (int s = 0; s < S; ++s) acc[s] = 0.f;
      mm64(xb, Wt, lane, acc);
      float bov = bo[layer * D + lane];
      #pragma unroll
      for (int s = 0; s < S; ++s) h[s] += acc[s] + bov;
    }

    // ---- FFN (two K=64 halves), pre-LN ----
    float g2v = g2[layer * D + lane], be2v = be2[layer * D + lane];
    float hnreg[S];
    layernorm<true>(h, xb, lane, g2v, be2v, hnreg);
    float b2v = b2[layer * D + lane];

    #pragma unroll 1
    for (int half = 0; half < 2; ++half) {
      __syncthreads();
      stageW(Wt, w1 + layer * D * DFF + half * 64, DFF, tid);
      __syncthreads();
      {
        float a[S];
        #pragma unroll
        for (int s = 0; s < S; ++s) a[s] = 0.f;
        mm64(xb, Wt, lane, a);
        float b1v = b1[layer * DFF + half * 64 + lane];
        #pragma unroll
        for (int s = 0; s < S; ++s)
          xb[s * XPITCH + lane] = fmaxf(a[s] + b1v, 0.f);  // relu(a1) half
      }
      __syncthreads();
      stageW(Wt, w2 + layer * DFF * D + half * 64 * D, D, tid);
      __syncthreads();
      {
        float a2[S];
        #pragma unroll
        for (int s = 0; s < S; ++s) a2[s] = 0.f;
        mm64(xb, Wt, lane, a2);
        #pragma unroll
        for (int s = 0; s < S; ++s) h[s] += a2[s];
      }
      if (half == 0) {
        #pragma unroll
        for (int s = 0; s < S; ++s) xb[s * XPITCH + lane] = hnreg[s];
      }
    }
    #pragma unroll
    for (int s = 0; s < S; ++s) h[s] += b2v;
  }

  // ---- head: mean-pool -> 64x32 relu MLP -> 32x1 -> tanh ----
  {
    float p = 0.f;
    #pragma unroll
    for (int s = 0; s < S; ++s) p += h[s];
    p *= (1.f / 32.f);
    xb[lane] = p;
    float r = 0.f;
    #pragma unroll
    for (int dd = 0; dd < 64; ++dd)
      r = fmaf(xb[dd], hw1[dd * 32 + (lane & 31)], r);
    r = fmaxf(r + hb1[lane & 31], 0.f);
    float t = r * hw2[lane & 31];
    t += __shfl_xor(t, 1); t += __shfl_xor(t, 2); t += __shfl_xor(t, 4);
    t += __shfl_xor(t, 8); t += __shfl_xor(t, 16);
    float o = tanhf(t + hb2[0]);
    if (lane == 0) out[elem] = o;
  }
}

extern "C" void kernel_launch(void* const* d_in, const int* in_sizes, int n_in,
                              void* d_out, int out_size, void* d_ws, size_t ws_size,
                              hipStream_t stream) {
  (void)in_sizes; (void)n_in; (void)d_ws; (void)ws_size; (void)out_size;
  const float* x    = (const float*)d_in[0];
  const float* w_in = (const float*)d_in[1];
  const float* b_in = (const float*)d_in[2];
  const float* pos  = (const float*)d_in[3];
  const float* wq   = (const float*)d_in[4];
  const float* wk   = (const float*)d_in[5];
  const float* wvw  = (const float*)d_in[6];
  const float* wo   = (const float*)d_in[7];
  const float* bo   = (const float*)d_in[8];
  const float* g1   = (const float*)d_in[9];
  const float* be1  = (const float*)d_in[10];
  const float* g2   = (const float*)d_in[11];
  const float* be2  = (const float*)d_in[12];
  const float* w1   = (const float*)d_in[13];
  const float* b1   = (const float*)d_in[14];
  const float* w2   = (const float*)d_in[15];
  const float* b2   = (const float*)d_in[16];
  const float* hw1  = (const float*)d_in[17];
  const float* hb1  = (const float*)d_in[18];
  const float* hw2  = (const float*)d_in[19];
  const float* hb2  = (const float*)d_in[20];
  float* out = (float*)d_out;

  dim3 grid(Bsz / NB), block(256);
  hipLaunchKernelGGL(tlob_kernel, grid, block, 0, stream,
                     x, w_in, b_in, pos, wq, wk, wvw, wo, bo, g1, be1, g2, be2,
                     w1, b1, w2, b2, hw1, hb1, hw2, hb2, out);
}

// Round 2
// 749.981 us; speedup vs baseline: 9.2871x; 9.2871x over previous
//
#include <hip/hip_runtime.h>
#include <cmath>

typedef _Float16 h8_t __attribute__((ext_vector_type(8)));
typedef float f4_t __attribute__((ext_vector_type(4)));

constexpr int Bsz = 32768, S = 32, F = 10, Dm = 64, Ln = 2, DFF = 128;
constexpr int ZP = 72;   // zone / weight-tile pitch in halves (144B, 16B-aligned)
constexpr int VP = 40;   // vT pitch in halves (80B, 16B-aligned)
constexpr int NB = 4;    // batch elems (waves) per block

constexpr int WT_H   = 64 * ZP;                    // 4608 halves
constexpr int ZONE_H = 32 * ZP;                    // 2304 halves
constexpr int VT_H   = 64 * VP;                    // 2560 halves
constexpr int SMEM_H = WT_H + NB * (ZONE_H + VT_H); // 24064 halves = 48128 B

__device__ __forceinline__ f4_t mfma16(h8_t a, h8_t b, f4_t c) {
  return __builtin_amdgcn_mfma_f32_16x16x32_f16(a, b, c, 0, 0, 0);
}
__device__ __forceinline__ h8_t ldfrag(const _Float16* p) {
  return *(const h8_t*)p;
}

__global__ __launch_bounds__(256, 2)
void tlob_kernel(const float* __restrict__ x,   const float* __restrict__ w_in,
                 const float* __restrict__ b_in, const float* __restrict__ pos,
                 const float* __restrict__ wq,  const float* __restrict__ wk,
                 const float* __restrict__ wv,  const float* __restrict__ wo,
                 const float* __restrict__ bo,  const float* __restrict__ g1,
                 const float* __restrict__ be1, const float* __restrict__ g2,
                 const float* __restrict__ be2, const float* __restrict__ w1,
                 const float* __restrict__ b1,  const float* __restrict__ w2,
                 const float* __restrict__ b2,  const float* __restrict__ hw1,
                 const float* __restrict__ hb1, const float* __restrict__ hw2,
                 const float* __restrict__ hb2, float* __restrict__ out) {
  __shared__ __align__(16) _Float16 smem[SMEM_H];

  const int tid  = threadIdx.x;
  const int lane = tid & 63;
  const int wid  = tid >> 6;
  const int elem = blockIdx.x * NB + wid;

  _Float16* Wt   = smem;
  _Float16* zone = smem + WT_H + wid * ZONE_H;
  _Float16* vT   = smem + WT_H + NB * ZONE_H + wid * VT_H;

  const int l15 = lane & 15;
  const int lk8 = (lane >> 4) << 3;   // k-slot byte-group base (halves)
  const int r0b = (lane >> 4) << 2;   // C-row base within 16x16 tile
  int col4[4];
  #pragma unroll
  for (int nt = 0; nt < 4; ++nt) col4[nt] = l15 + 16 * nt;

  f4_t z4;  { z4[0]=0.f; z4[1]=0.f; z4[2]=0.f; z4[3]=0.f; }
  h8_t hz;
  #pragma unroll
  for (int j = 0; j < 8; ++j) hz[j] = (_Float16)0.f;

  // ---------- helpers ----------
  auto stage64 = [&](const float* src, int rowStride) {
    #pragma unroll
    for (int i = 0; i < 16; ++i) {
      int idx = tid + i * 256;
      int n = idx & 63, k = idx >> 6;
      Wt[n * ZP + k] = (_Float16)src[k * rowStride + n];
    }
  };
  auto wfrag = [&](int nt, int kt) -> h8_t {
    return ldfrag(&Wt[(l15 + 16 * nt) * ZP + kt * 32 + lk8]);
  };
  auto zfrag = [&](int i1, int i2) -> h8_t {
    return ldfrag(&zone[(l15 + 16 * i1) * ZP + i2 * 32 + lk8]);
  };
  auto writeC = [&](int mt, int nt, f4_t v) {
    int r = 16 * mt + r0b, c = l15 + 16 * nt;
    #pragma unroll
    for (int q = 0; q < 4; ++q) zone[(r + q) * ZP + c] = (_Float16)v[q];
  };

  // ---------- input staging ----------
  #pragma unroll
  for (int i = 0; i < 8; ++i) {           // w_in^T, K zero-padded to 32
    int idx = tid + i * 256;
    int n = idx & 63, k = idx >> 6;
    Wt[n * ZP + k] = (_Float16)((k < F) ? w_in[k * Dm + n] : 0.f);
  }
  {                                       // zero x pad cols [F,32)
    int row = lane >> 1, c0 = F + (lane & 1) * 11;
    #pragma unroll
    for (int j = 0; j < 11; ++j) zone[row * ZP + c0 + j] = (_Float16)0.f;
  }
  {                                       // load x -> zone[s][f] fp16
    const float* xe = x + (size_t)elem * (S * F);
    #pragma unroll
    for (int i = 0; i < 5; ++i) {
      int idx = lane * 5 + i;
      zone[(idx / F) * ZP + (idx % F)] = (_Float16)xe[idx];
    }
  }
  __syncthreads();

  // ---------- input projection: h = x @ w_in + b_in + pos ----------
  f4_t hacc[2][4];
  {
    h8_t xa[2];
    #pragma unroll
    for (int mt = 0; mt < 2; ++mt) xa[mt] = zfrag(mt, 0);
    #pragma unroll
    for (int nt = 0; nt < 4; ++nt) {
      float bv = b_in[col4[nt]];
      h8_t wb = wfrag(nt, 0);
      #pragma unroll
      for (int mt = 0; mt < 2; ++mt) {
        f4_t ini;
        #pragma unroll
        for (int q = 0; q < 4; ++q)
          ini[q] = pos[(16 * mt + r0b + q) * Dm + col4[nt]] + bv;
        hacc[mt][nt] = mfma16(xa[mt], wb, ini);
      }
    }
  }

  // ---------- LN helper ----------
  auto doLN = [&](const float* g, const float* be, h8_t fr[2][2]) {
    float gv[4], bv[4];
    #pragma unroll
    for (int nt = 0; nt < 4; ++nt) { gv[nt] = g[col4[nt]]; bv[nt] = be[col4[nt]]; }
    #pragma unroll
    for (int mt = 0; mt < 2; ++mt) {
      f4_t ps = hacc[mt][0] + hacc[mt][1] + hacc[mt][2] + hacc[mt][3];
      f4_t pq = hacc[mt][0] * hacc[mt][0] + hacc[mt][1] * hacc[mt][1] +
                hacc[mt][2] * hacc[mt][2] + hacc[mt][3] * hacc[mt][3];
      #pragma unroll
      for (int m = 1; m <= 8; m <<= 1) {
        #pragma unroll
        for (int q = 0; q < 4; ++q) {
          ps[q] += __shfl_xor(ps[q], m);
          pq[q] += __shfl_xor(pq[q], m);
        }
      }
      f4_t muv, rsv;
      #pragma unroll
      for (int q = 0; q < 4; ++q) {
        float mu = ps[q] * (1.f / 64.f);
        float var = pq[q] * (1.f / 64.f) - mu * mu;
        muv[q] = mu; rsv[q] = rsqrtf(var + 1e-5f);
      }
      #pragma unroll
      for (int nt = 0; nt < 4; ++nt) {
        int r = 16 * mt + r0b, c = col4[nt];
        #pragma unroll
        for (int q = 0; q < 4; ++q) {
          float hn = (hacc[mt][nt][q] - muv[q]) * rsv[q] * gv[nt] + bv[nt];
          zone[(r + q) * ZP + c] = (_Float16)hn;
        }
      }
    }
    #pragma unroll
    for (int i1 = 0; i1 < 2; ++i1)
      #pragma unroll
      for (int i2 = 0; i2 < 2; ++i2) fr[i1][i2] = zfrag(i1, i2);
  };

  // ---------- layers ----------
  #pragma unroll 1
  for (int layer = 0; layer < Ln; ++layer) {
    const float* wk_l = wk + layer * Dm * Dm;
    const float* wv_l = wv + layer * Dm * Dm;
    const float* wq_l = wq + layer * Dm * Dm;
    const float* wo_l = wo + layer * Dm * Dm;
    float bov[4], b2v[4];
    #pragma unroll
    for (int nt = 0; nt < 4; ++nt) {
      bov[nt] = bo[layer * Dm + col4[nt]];
      b2v[nt] = b2[layer * Dm + col4[nt]];
    }

    __syncthreads();
    stage64(wk_l, Dm);
    h8_t hnf[2][2];
    doLN(g1 + layer * Dm, be1 + layer * Dm, hnf);
    __syncthreads();

    // ---- k projection -> zone -> k fragments (B-side of QK^T) ----
    h8_t kfr[2][2];
    {
      h8_t wb[4][2];
      #pragma unroll
      for (int nt = 0; nt < 4; ++nt)
        #pragma unroll
        for (int kt = 0; kt < 2; ++kt) wb[nt][kt] = wfrag(nt, kt);
      #pragma unroll
      for (int mt = 0; mt < 2; ++mt)
        #pragma unroll
        for (int nt = 0; nt < 4; ++nt) {
          f4_t acc = mfma16(hnf[mt][0], wb[nt][0], z4);
          acc = mfma16(hnf[mt][1], wb[nt][1], acc);
          writeC(mt, nt, acc);
        }
      #pragma unroll
      for (int i1 = 0; i1 < 2; ++i1)
        #pragma unroll
        for (int kt = 0; kt < 2; ++kt) kfr[i1][kt] = zfrag(i1, kt);
    }

    __syncthreads();
    stage64(wv_l, Dm);
    __syncthreads();

    // ---- vT = Wv^T @ hn^T  (A = staged Wv^T, B = hn) ----
    #pragma unroll
    for (int mtd = 0; mtd < 4; ++mtd)
      #pragma unroll
      for (int nts = 0; nts < 2; ++nts) {
        f4_t acc = mfma16(wfrag(mtd, 0), hnf[nts][0], z4);
        acc = mfma16(wfrag(mtd, 1), hnf[nts][1], acc);
        int r = 16 * mtd + r0b, c = l15 + 16 * nts;
        #pragma unroll
        for (int q = 0; q < 4; ++q) vT[(r + q) * VP + c] = (_Float16)acc[q];
      }

    __syncthreads();
    stage64(wq_l, Dm);
    __syncthreads();

    // ---- q projection -> zone -> q fragments (A-side of QK^T) ----
    h8_t qf[2][2];
    {
      h8_t wb[4][2];
      #pragma unroll
      for (int nt = 0; nt < 4; ++nt)
        #pragma unroll
        for (int kt = 0; kt < 2; ++kt) wb[nt][kt] = wfrag(nt, kt);
      #pragma unroll
      for (int mt = 0; mt < 2; ++mt)
        #pragma unroll
        for (int nt = 0; nt < 4; ++nt) {
          f4_t acc = mfma16(hnf[mt][0], wb[nt][0], z4);
          acc = mfma16(hnf[mt][1], wb[nt][1], acc);
          writeC(mt, nt, acc);
        }
      #pragma unroll
      for (int i1 = 0; i1 < 2; ++i1)
        #pragma unroll
        for (int kt = 0; kt < 2; ++kt) qf[i1][kt] = zfrag(i1, kt);
    }

    __syncthreads();
    stage64(wo_l, Dm);   // overlap Wo staging with attention

    // ---- attention, per head ----
    f4_t ctxf[2][4];
    #pragma unroll
    for (int hd = 0; hd < 4; ++hd) {
      int kt = hd >> 1;
      bool keep = ((hd & 1) == 0) ? (lane < 32) : (lane >= 32);
      h8_t b0 = keep ? kfr[0][kt] : hz;
      h8_t b1 = keep ? kfr[1][kt] : hz;
      f4_t sc[2][2];
      #pragma unroll
      for (int mt = 0; mt < 2; ++mt) {
        sc[mt][0] = mfma16(qf[mt][kt], b0, z4);
        sc[mt][1] = mfma16(qf[mt][kt], b1, z4);
      }
      // exp (scale 1/sqrt(16)=0.25 folded; clamp guards fp16 overflow)
      f4_t p[2][2], sm[2];
      #pragma unroll
      for (int mt = 0; mt < 2; ++mt) {
        #pragma unroll
        for (int n2 = 0; n2 < 2; ++n2)
          #pragma unroll
          for (int q = 0; q < 4; ++q)
            p[mt][n2][q] = __expf(fminf(sc[mt][n2][q], 40.f) * 0.25f);
        sm[mt] = p[mt][0] + p[mt][1];
      }
      #pragma unroll
      for (int m = 1; m <= 8; m <<= 1)
        #pragma unroll
        for (int mt = 0; mt < 2; ++mt)
          #pragma unroll
          for (int q = 0; q < 4; ++q) sm[mt][q] += __shfl_xor(sm[mt][q], m);
      // P -> zone (cols 0..31), read back as A-frags, PV
      #pragma unroll
      for (int mt = 0; mt < 2; ++mt)
        #pragma unroll
        for (int n2 = 0; n2 < 2; ++n2) writeC(mt, n2, p[mt][n2]);
      h8_t pA0 = zfrag(0, 0), pA1 = zfrag(1, 0);
      h8_t vB = ldfrag(&vT[(hd * 16 + l15) * VP + lk8]);
      f4_t c0 = mfma16(pA0, vB, z4);
      f4_t c1 = mfma16(pA1, vB, z4);
      #pragma unroll
      for (int q = 0; q < 4; ++q) {
        ctxf[0][hd][q] = c0[q] * __builtin_amdgcn_rcpf(sm[0][q]);
        ctxf[1][hd][q] = c1[q] * __builtin_amdgcn_rcpf(sm[1][q]);
      }
    }

    // ---- ctx -> zone, O projection (residual via C-in = h) ----
    #pragma unroll
    for (int mt = 0; mt < 2; ++mt)
      #pragma unroll
      for (int hd = 0; hd < 4; ++hd) writeC(mt, hd, ctxf[mt][hd]);
    h8_t ca[2][2];
    #pragma unroll
    for (int i1 = 0; i1 < 2; ++i1)
      #pragma unroll
      for (int kt = 0; kt < 2; ++kt) ca[i1][kt] = zfrag(i1, kt);
    __syncthreads();   // Wo staged
    {
      h8_t wb[4][2];
      #pragma unroll
      for (int nt = 0; nt < 4; ++nt)
        #pragma unroll
        for (int kt = 0; kt < 2; ++kt) wb[nt][kt] = wfrag(nt, kt);
      #pragma unroll
      for (int mt = 0; mt < 2; ++mt)
        #pragma unroll
        for (int nt = 0; nt < 4; ++nt) {
          f4_t acc = mfma16(ca[mt][0], wb[nt][0], hacc[mt][nt]);
          acc = mfma16(ca[mt][1], wb[nt][1], acc);
          #pragma unroll
          for (int q = 0; q < 4; ++q) hacc[mt][nt][q] = acc[q] + bov[nt];
        }
    }

    // ---- FFN ----
    __syncthreads();
    stage64(w1 + layer * Dm * DFF + 0 * 64, DFF);
    h8_t hn2f[2][2];
    doLN(g2 + layer * Dm, be2 + layer * Dm, hn2f);
    f4_t facc[2][4];
    #pragma unroll
    for (int mt = 0; mt < 2; ++mt)
      #pragma unroll
      for (int nt = 0; nt < 4; ++nt) facc[mt][nt] = hacc[mt][nt];
    __syncthreads();

    #pragma unroll 1
    for (int hf = 0; hf < 2; ++hf) {
      // FFN1 half: relu(hn2 @ W1[:,hf*64:+64] + b1) -> zone
      h8_t rf[2][2];
      {
        h8_t wb[4][2];
        #pragma unroll
        for (int nt = 0; nt < 4; ++nt)
          #pragma unroll
          for (int kt = 0; kt < 2; ++kt) wb[nt][kt] = wfrag(nt, kt);
        #pragma unroll
        for (int mt = 0; mt < 2; ++mt)
          #pragma unroll
          for (int nt = 0; nt < 4; ++nt) {
            float b1v = b1[layer * DFF + hf * 64 + col4[nt]];
            f4_t bb; 
            #pragma unroll
            for (int q = 0; q < 4; ++q) bb[q] = b1v;
            f4_t acc = mfma16(hn2f[mt][0], wb[nt][0], bb);
            acc = mfma16(hn2f[mt][1], wb[nt][1], acc);
            #pragma unroll
            for (int q = 0; q < 4; ++q) acc[q] = fmaxf(acc[q], 0.f);
            writeC(mt, nt, acc);
          }
        #pragma unroll
        for (int i1 = 0; i1 < 2; ++i1)
          #pragma unroll
          for (int kt = 0; kt < 2; ++kt) rf[i1][kt] = zfrag(i1, kt);
      }
      __syncthreads();
      stage64(w2 + layer * DFF * Dm + hf * 64 * Dm, Dm);
      __syncthreads();
      // FFN2 k-half accumulate
      {
        h8_t wb[4][2];
        #pragma unroll
        for (int nt = 0; nt < 4; ++nt)
          #pragma unroll
          for (int kt = 0; kt < 2; ++kt) wb[nt][kt] = wfrag(nt, kt);
        #pragma unroll
        for (int mt = 0; mt < 2; ++mt)
          #pragma unroll
          for (int nt = 0; nt < 4; ++nt) {
            f4_t acc = mfma16(rf[mt][0], wb[nt][0], facc[mt][nt]);
            facc[mt][nt] = mfma16(rf[mt][1], wb[nt][1], acc);
          }
      }
      if (hf == 0) {
        __syncthreads();
        stage64(w1 + layer * Dm * DFF + 1 * 64, DFF);
        __syncthreads();
      }
    }
    #pragma unroll
    for (int mt = 0; mt < 2; ++mt)
      #pragma unroll
      for (int nt = 0; nt < 4; ++nt)
        #pragma unroll
        for (int q = 0; q < 4; ++q) hacc[mt][nt][q] = facc[mt][nt][q] + b2v[nt];
  }

  // ---------- head: mean-pool -> relu MLP -> tanh ----------
  __syncthreads();
  {
    float* Wtf = (float*)smem;   // reuse weight area as fp32 scratch
    #pragma unroll
    for (int i = 0; i < 8; ++i) {
      int idx = tid + i * 256;                // 2048 = 64*32
      Wtf[(idx >> 5) * 33 + (idx & 31)] = hw1[idx];
    }
    if (tid < 32) {
      Wtf[2112 + tid] = hw2[tid];
      Wtf[2144 + tid] = hb1[tid];
    }
    if (tid == 0) Wtf[2176] = hb2[0];
    __syncthreads();

    float* pf = (float*)vT;      // per-wave fp32 scratch for pooled vector
    #pragma unroll
    for (int nt = 0; nt < 4; ++nt) {
      float s = 0.f;
      #pragma unroll
      for (int mt = 0; mt < 2; ++mt)
        #pragma unroll
        for (int q = 0; q < 4; ++q) s += hacc[mt][nt][q];
      s += __shfl_xor(s, 16);
      s += __shfl_xor(s, 32);
      pf[col4[nt]] = s * (1.f / 32.f);
    }
    int j = lane & 31;
    float r = 0.f;
    #pragma unroll
    for (int d = 0; d < 64; ++d) r = fmaf(pf[d], Wtf[d * 33 + j], r);
    r = fmaxf(r + Wtf[2144 + j], 0.f);
    float t = r * Wtf[2112 + j];
    t += __shfl_xor(t, 1); t += __shfl_xor(t, 2); t += __shfl_xor(t, 4);
    t += __shfl_xor(t, 8); t += __shfl_xor(t, 16);
    if (lane == 0) out[elem] = tanhf(t + Wtf[2176]);
  }
}

extern "C" void kernel_launch(void* const* d_in, const int* in_sizes, int n_in,
                              void* d_out, int out_size, void* d_ws, size_t ws_size,
                              hipStream_t stream) {
  (void)in_sizes; (void)n_in; (void)d_ws; (void)ws_size; (void)out_size;
  const float* x    = (const float*)d_in[0];
  const float* w_in = (const float*)d_in[1];
  const float* b_in = (const float*)d_in[2];
  const float* pos  = (const float*)d_in[3];
  const float* wq   = (const float*)d_in[4];
  const float* wk   = (const float*)d_in[5];
  const float* wv   = (const float*)d_in[6];
  const float* wo   = (const float*)d_in[7];
  const float* bo   = (const float*)d_in[8];
  const float* g1   = (const float*)d_in[9];
  const float* be1  = (const float*)d_in[10];
  const float* g2   = (const float*)d_in[11];
  const float* be2  = (const float*)d_in[12];
  const float* w1   = (const float*)d_in[13];
  const float* b1   = (const float*)d_in[14];
  const float* w2   = (const float*)d_in[15];
  const float* b2   = (const float*)d_in[16];
  const float* hw1  = (const float*)d_in[17];
  const float* hb1  = (const float*)d_in[18];
  const float* hw2  = (const float*)d_in[19];
  const float* hb2  = (const float*)d_in[20];
  float* out = (float*)d_out;

  dim3 grid(Bsz / NB), block(256);
  hipLaunchKernelGGL(tlob_kernel, grid, block, 0, stream,
                     x, w_in, b_in, pos, wq, wk, wv, wo, bo, g1, be1, g2, be2,
                     w1, b1, w2, b2, hw1, hb1, hw2, hb2, out);
}

// Round 3
// 564.503 us; speedup vs baseline: 12.3386x; 1.3286x over previous
//
#include <hip/hip_runtime.h>
#include <cmath>

typedef _Float16 h8_t __attribute__((ext_vector_type(8)));
typedef float f4_t __attribute__((ext_vector_type(4)));

constexpr int Bsz = 32768, S = 32, F = 10, Dm = 64, Ln = 2, DFF = 128;
constexpr int ZP = 72;   // zone pitch (halves); rows 16B-aligned
constexpr int VP = 40;   // vT pitch (halves)
constexpr int NB = 2;    // waves (batch elems) per block

constexpr int ZONE_H = S * ZP;                 // 2304 halves
constexpr int VT_H   = Dm * VP;                // 2560 halves
constexpr int SMEM_H = NB * (ZONE_H + VT_H);   // 9728 halves = 19456 B

constexpr int NFRAG = 4 + Ln * 64;             // 132 weight fragments
constexpr size_t PB_OFF = (size_t)NFRAG * 512 * 2;  // bytes; then 8 f4-frags pos+bias

// ---------------- weight pre-pack kernel ----------------
// Fragment f, lane l (l15=l&15, lk8=(l>>4)*8): 8 halves = W[kbase+j][n],
// n = 16*nt + l15, kbase = kt*32 + lk8. Layout per matmul defined below.
__global__ __launch_bounds__(256, 2)
void prep_kernel(const float* __restrict__ w_in, const float* __restrict__ b_in,
                 const float* __restrict__ pos,
                 const float* __restrict__ wq, const float* __restrict__ wk,
                 const float* __restrict__ wv, const float* __restrict__ wo,
                 const float* __restrict__ w1, const float* __restrict__ w2,
                 _Float16* __restrict__ wsf, float* __restrict__ pbf) {
  int gid = blockIdx.x * 256 + threadIdx.x;
  int lane = gid & 63;
  int l15 = lane & 15, lk8 = (lane >> 4) << 3;
  if (gid < NFRAG * 64) {
    int frag = gid >> 6;
    float vals[8];
    if (frag < 4) {                       // w_in: nt=frag, kt=0, k>=10 zero
      int n = 16 * frag + l15;
      #pragma unroll
      for (int j = 0; j < 8; ++j) {
        int k = lk8 + j;
        vals[j] = (k < F) ? w_in[k * Dm + n] : 0.f;
      }
    } else {
      int f = frag - 4;
      int layer = f >> 6; f &= 63;
      const float* W; int ncols, n, kbase;
      if (f < 32) {                       // K(0-7) V(8-15) Q(16-23) O(24-31), g=kt*4+nt
        int sub = f >> 3, g = f & 7;
        int nt = g & 3, kt = g >> 2;
        W = ((sub == 0) ? wk : (sub == 1) ? wv : (sub == 2) ? wq : wo) + layer * Dm * Dm;
        ncols = Dm; n = 16 * nt + l15; kbase = kt * 32 + lk8;
      } else if (f < 48) {                // W1: g=kt*8+nt (nt 0..7)
        int g = f - 32, nt = g & 7, kt = g >> 3;
        W = w1 + layer * Dm * DFF; ncols = DFF; n = 16 * nt + l15; kbase = kt * 32 + lk8;
      } else {                            // W2: g=kt*4+nt (kt 0..3)
        int g = f - 48, nt = g & 3, kt = g >> 2;
        W = w2 + layer * DFF * Dm; ncols = Dm; n = 16 * nt + l15; kbase = kt * 32 + lk8;
      }
      #pragma unroll
      for (int j = 0; j < 8; ++j) vals[j] = W[(kbase + j) * ncols + n];
    }
    h8_t o;
    #pragma unroll
    for (int j = 0; j < 8; ++j) o[j] = (_Float16)vals[j];
    *(h8_t*)&wsf[(size_t)gid * 8] = o;
  } else if (gid < NFRAG * 64 + 8 * 64) { // pos+b_in in C-frag layout, f4 per lane
    int r = gid - NFRAG * 64;
    int pb = r >> 6;
    int mt = pb >> 2, nt = pb & 3;
    int row = 16 * mt + ((lane >> 4) << 2);
    int col = 16 * nt + l15;
    f4_t v;
    #pragma unroll
    for (int q = 0; q < 4; ++q) v[q] = pos[(row + q) * Dm + col] + b_in[col];
    *(f4_t*)&pbf[(size_t)r * 4] = v;
  }
}

// ---------------- fused main kernel: 1 wave per batch element ----------------
__global__ __launch_bounds__(128, 4)
void tlob_kernel(const float* __restrict__ x,
                 const float* __restrict__ g1, const float* __restrict__ be1,
                 const float* __restrict__ g2, const float* __restrict__ be2,
                 const float* __restrict__ bo, const float* __restrict__ b1,
                 const float* __restrict__ b2, const float* __restrict__ hw1,
                 const float* __restrict__ hb1, const float* __restrict__ hw2,
                 const float* __restrict__ hb2,
                 const _Float16* __restrict__ wsf, const float* __restrict__ pbf,
                 float* __restrict__ out) {
  __shared__ __align__(16) _Float16 smem[SMEM_H];
  const int tid = threadIdx.x;
  const int lane = tid & 63;
  const int wid = tid >> 6;
  const int elem = blockIdx.x * NB + wid;

  _Float16* zone = smem + wid * ZONE_H;
  _Float16* vT = smem + NB * ZONE_H + wid * VT_H;

  const int l15 = lane & 15;
  const int G = lane >> 4;
  const int lk8 = G << 3;          // k-slot base (halves); also C-write XOR key
  const int r0b = G << 2;          // C-row base
  const int swzR = ((l15 >> 2) & 3) << 3;  // XOR key for rows l15+16t
  int col4[4];
  #pragma unroll
  for (int nt = 0; nt < 4; ++nt) col4[nt] = l15 + 16 * nt;

  const h8_t* FR = (const h8_t*)wsf;
  auto ldf = [&](int f) -> h8_t { return FR[f * 64 + lane]; };

  f4_t z4; z4[0] = 0.f; z4[1] = 0.f; z4[2] = 0.f; z4[3] = 0.f;
  h8_t hz;
  #pragma unroll
  for (int j = 0; j < 8; ++j) hz[j] = (_Float16)0.f;

  auto mfma = [&](h8_t a, h8_t b, f4_t c) -> f4_t {
    return __builtin_amdgcn_mfma_f32_16x16x32_f16(a, b, c, 0, 0, 0);
  };
  // C-layout store: rows 16mt+r0b+q → XOR key = lk8 (constant per lane)
  auto cstore = [&](_Float16* buf, int pitch, int mt, int col, f4_t v, float scale) {
    int c = col ^ lk8;
    int r = 16 * mt + r0b;
    #pragma unroll
    for (int q = 0; q < 4; ++q) buf[(r + q) * pitch + c] = (_Float16)(v[q] * scale);
  };
  // A/B fragment read: row l15+16i1 → XOR key = swzR
  auto zfrag = [&](int i1, int i2) -> h8_t {
    return *(const h8_t*)&zone[(l15 + 16 * i1) * ZP + ((i2 * 32 + lk8) ^ swzR)];
  };

  // ---- x fragments straight from global (K padded 10->32) ----
  h8_t xa[2];
  #pragma unroll
  for (int mt = 0; mt < 2; ++mt) {
    const float* xr = x + (size_t)elem * (S * F) + (16 * mt + l15) * F;
    h8_t v = hz;
    #pragma unroll
    for (int j = 0; j < 8; ++j) {
      int f = lk8 + j;
      if (f < F) v[j] = (_Float16)xr[f];
    }
    xa[mt] = v;
  }

  // ---- input projection: h = x@w_in + b_in + pos (C-in from packed pbf) ----
  f4_t hacc[2][4];
  #pragma unroll
  for (int nt = 0; nt < 4; ++nt) {
    h8_t wb = ldf(nt);
    #pragma unroll
    for (int mt = 0; mt < 2; ++mt) {
      f4_t ini = *(const f4_t*)&pbf[((size_t)(mt * 4 + nt) * 64 + lane) * 4];
      hacc[mt][nt] = mfma(xa[mt], wb, ini);
    }
  }

  // ---- LN (cross-lane over l15; in-lane over nt), write zone, read frags ----
  auto doLN = [&](const float* g, const float* be, h8_t fr[2][2]) {
    float gv[4], bv[4];
    #pragma unroll
    for (int nt = 0; nt < 4; ++nt) { gv[nt] = g[col4[nt]]; bv[nt] = be[col4[nt]]; }
    #pragma unroll
    for (int mt = 0; mt < 2; ++mt) {
      f4_t ps = hacc[mt][0] + hacc[mt][1] + hacc[mt][2] + hacc[mt][3];
      f4_t pq = hacc[mt][0] * hacc[mt][0] + hacc[mt][1] * hacc[mt][1] +
                hacc[mt][2] * hacc[mt][2] + hacc[mt][3] * hacc[mt][3];
      #pragma unroll
      for (int m = 1; m <= 8; m <<= 1) {
        #pragma unroll
        for (int q = 0; q < 4; ++q) {
          ps[q] += __shfl_xor(ps[q], m);
          pq[q] += __shfl_xor(pq[q], m);
        }
      }
      f4_t muv, rsv;
      #pragma unroll
      for (int q = 0; q < 4; ++q) {
        float mu = ps[q] * (1.f / 64.f);
        float var = pq[q] * (1.f / 64.f) - mu * mu;
        muv[q] = mu; rsv[q] = rsqrtf(var + 1e-5f);
      }
      #pragma unroll
      for (int nt = 0; nt < 4; ++nt) {
        int c = col4[nt] ^ lk8;
        int r = 16 * mt + r0b;
        #pragma unroll
        for (int q = 0; q < 4; ++q) {
          float hn = (hacc[mt][nt][q] - muv[q]) * rsv[q] * gv[nt] + bv[nt];
          zone[(r + q) * ZP + c] = (_Float16)hn;
        }
      }
    }
    #pragma unroll
    for (int i1 = 0; i1 < 2; ++i1)
      #pragma unroll
      for (int i2 = 0; i2 < 2; ++i2) fr[i1][i2] = zfrag(i1, i2);
  };

  // ---------------- layers ----------------
  #pragma unroll 1
  for (int layer = 0; layer < Ln; ++layer) {
    const int fb = 4 + layer * 64;   // frag base: K+0 V+8 Q+16 O+24 W1+32 W2+48
    float bov[4];
    #pragma unroll
    for (int nt = 0; nt < 4; ++nt) bov[nt] = bo[layer * Dm + col4[nt]];

    h8_t hnf[2][2];
    doLN(g1 + layer * Dm, be1 + layer * Dm, hnf);

    // ---- K projection -> zone -> A-frags (keys as rows) ----
    h8_t kA[2][2];
    {
      #pragma unroll
      for (int nt = 0; nt < 4; ++nt) {
        h8_t w0 = ldf(fb + 0 + 0 * 4 + nt), w1f = ldf(fb + 0 + 1 * 4 + nt);
        #pragma unroll
        for (int mt = 0; mt < 2; ++mt) {
          f4_t acc = mfma(hnf[mt][0], w0, z4);
          acc = mfma(hnf[mt][1], w1f, acc);
          cstore(zone, ZP, mt, col4[nt], acc, 1.f);
        }
      }
      #pragma unroll
      for (int i1 = 0; i1 < 2; ++i1)
        #pragma unroll
        for (int i2 = 0; i2 < 2; ++i2) kA[i1][i2] = zfrag(i1, i2);
    }

    // ---- vT = Wv^T @ hn^T (A = packed V frags, B = hn frags) -> vT LDS ----
    #pragma unroll
    for (int mtd = 0; mtd < 4; ++mtd) {
      h8_t a0 = ldf(fb + 8 + 0 * 4 + mtd), a1 = ldf(fb + 8 + 1 * 4 + mtd);
      #pragma unroll
      for (int nts = 0; nts < 2; ++nts) {
        f4_t acc = mfma(a0, hnf[nts][0], z4);
        acc = mfma(a1, hnf[nts][1], acc);
        cstore(vT, VP, mtd, l15 + 16 * nts, acc, 1.f);
      }
    }

    // ---- Q projection (scaled by 1/sqrt(HD)=0.25 at store) -> A-layout frags ----
    h8_t qf[2][2];
    {
      #pragma unroll
      for (int nt = 0; nt < 4; ++nt) {
        h8_t w0 = ldf(fb + 16 + 0 * 4 + nt), w1f = ldf(fb + 16 + 1 * 4 + nt);
        #pragma unroll
        for (int mt = 0; mt < 2; ++mt) {
          f4_t acc = mfma(hnf[mt][0], w0, z4);
          acc = mfma(hnf[mt][1], w1f, acc);
          cstore(zone, ZP, mt, col4[nt], acc, 0.25f);
        }
      }
      #pragma unroll
      for (int i1 = 0; i1 < 2; ++i1)
        #pragma unroll
        for (int i2 = 0; i2 < 2; ++i2) qf[i1][i2] = zfrag(i1, i2);
    }

    // ---- attention: S^T = K@Q^T per head; lane-local softmax; PV ----
    f4_t ctxf[2][4];
    #pragma unroll
    for (int hd = 0; hd < 4; ++hd) {
      const int kt = hd >> 1;
      bool keep = ((hd & 1) == 0) ? (lane < 32) : (lane >= 32);
      h8_t a0 = keep ? kA[0][kt] : hz;
      h8_t a1 = keep ? kA[1][kt] : hz;
      f4_t p[2][2];   // [key-tile][query-tile]
      #pragma unroll
      for (int nq = 0; nq < 2; ++nq) {
        p[0][nq] = mfma(a0, qf[nq][kt], z4);
        p[1][nq] = mfma(a1, qf[nq][kt], z4);
      }
      #pragma unroll
      for (int nq = 0; nq < 2; ++nq) {
        #pragma unroll
        for (int mk = 0; mk < 2; ++mk)
          #pragma unroll
          for (int q = 0; q < 4; ++q) p[mk][nq][q] = __expf(p[mk][nq][q]);
        f4_t s4 = p[0][nq] + p[1][nq];
        float sm = s4[0] + s4[1] + s4[2] + s4[3];
        sm += __shfl_xor(sm, 16);
        sm += __shfl_xor(sm, 32);
        float inv = __builtin_amdgcn_rcpf(sm);
        #pragma unroll
        for (int mk = 0; mk < 2; ++mk)
          #pragma unroll
          for (int q = 0; q < 4; ++q) p[mk][nq][q] *= inv;
      }
      // P^T scatter: zone[query][key] (XOR key = swzR since row = 16nq+l15)
      #pragma unroll
      for (int nq = 0; nq < 2; ++nq)
        #pragma unroll
        for (int mk = 0; mk < 2; ++mk)
          #pragma unroll
          for (int q = 0; q < 4; ++q)
            zone[(16 * nq + l15) * ZP + ((16 * mk + r0b + q) ^ swzR)] =
                (_Float16)p[mk][nq][q];
      h8_t pA0 = zfrag(0, 0), pA1 = zfrag(1, 0);
      h8_t vB = *(const h8_t*)&vT[(hd * 16 + l15) * VP + (lk8 ^ swzR)];
      ctxf[0][hd] = mfma(pA0, vB, z4);
      ctxf[1][hd] = mfma(pA1, vB, z4);
    }

    // ---- ctx -> zone -> A-frags; O projection with residual C-in ----
    #pragma unroll
    for (int mt = 0; mt < 2; ++mt)
      #pragma unroll
      for (int hd = 0; hd < 4; ++hd) cstore(zone, ZP, mt, col4[hd], ctxf[mt][hd], 1.f);
    h8_t ca[2][2];
    #pragma unroll
    for (int i1 = 0; i1 < 2; ++i1)
      #pragma unroll
      for (int i2 = 0; i2 < 2; ++i2) ca[i1][i2] = zfrag(i1, i2);
    #pragma unroll
    for (int nt = 0; nt < 4; ++nt) {
      h8_t w0 = ldf(fb + 24 + 0 * 4 + nt), w1f = ldf(fb + 24 + 1 * 4 + nt);
      #pragma unroll
      for (int mt = 0; mt < 2; ++mt) {
        f4_t acc = mfma(ca[mt][0], w0, hacc[mt][nt]);
        acc = mfma(ca[mt][1], w1f, acc);
        #pragma unroll
        for (int q = 0; q < 4; ++q) hacc[mt][nt][q] = acc[q] + bov[nt];
      }
    }

    // ---- FFN: LN2 then two K=64 halves, accumulate into hacc (residual) ----
    h8_t hn2f[2][2];
    doLN(g2 + layer * Dm, be2 + layer * Dm, hn2f);
    #pragma unroll 1
    for (int hf = 0; hf < 2; ++hf) {
      // FFN1 half: relu(hn2 @ W1[:, hf*64 .. +64) + b1) -> zone cols 0..63
      #pragma unroll
      for (int ntl = 0; ntl < 4; ++ntl) {
        int ntg = hf * 4 + ntl;
        h8_t w0 = ldf(fb + 32 + 0 * 8 + ntg), w1f = ldf(fb + 32 + 1 * 8 + ntg);
        float b1v = b1[layer * DFF + hf * 64 + col4[ntl]];
        f4_t bb; bb[0] = b1v; bb[1] = b1v; bb[2] = b1v; bb[3] = b1v;
        #pragma unroll
        for (int mt = 0; mt < 2; ++mt) {
          f4_t acc = mfma(hn2f[mt][0], w0, bb);
          acc = mfma(hn2f[mt][1], w1f, acc);
          #pragma unroll
          for (int q = 0; q < 4; ++q) acc[q] = fmaxf(acc[q], 0.f);
          cstore(zone, ZP, mt, col4[ntl], acc, 1.f);
        }
      }
      h8_t rf[2][2];
      #pragma unroll
      for (int i1 = 0; i1 < 2; ++i1)
        #pragma unroll
        for (int i2 = 0; i2 < 2; ++i2) rf[i1][i2] = zfrag(i1, i2);
      // FFN2 half-K accumulate into hacc
      #pragma unroll
      for (int nt = 0; nt < 4; ++nt) {
        h8_t w0 = ldf(fb + 48 + (hf * 2 + 0) * 4 + nt);
        h8_t w1f = ldf(fb + 48 + (hf * 2 + 1) * 4 + nt);
        #pragma unroll
        for (int mt = 0; mt < 2; ++mt) {
          f4_t acc = mfma(rf[mt][0], w0, hacc[mt][nt]);
          hacc[mt][nt] = mfma(rf[mt][1], w1f, acc);
        }
      }
    }
    #pragma unroll
    for (int mt = 0; mt < 2; ++mt)
      #pragma unroll
      for (int nt = 0; nt < 4; ++nt) {
        float b2v = b2[layer * Dm + col4[nt]];
        #pragma unroll
        for (int q = 0; q < 4; ++q) hacc[mt][nt][q] += b2v;
      }
  }

  // ---------------- head: mean-pool -> 64x32 relu MLP -> 32x1 -> tanh ----------------
  {
    float* pf = (float*)zone;
    #pragma unroll
    for (int nt = 0; nt < 4; ++nt) {
      float s = 0.f;
      #pragma unroll
      for (int mt = 0; mt < 2; ++mt)
        #pragma unroll
        for (int q = 0; q < 4; ++q) s += hacc[mt][nt][q];
      s += __shfl_xor(s, 16);
      s += __shfl_xor(s, 32);
      pf[col4[nt]] = s * (1.f / 32.f);
    }
    int j = lane & 31;
    float r = hb1[j];
    #pragma unroll
    for (int dd = 0; dd < 64; ++dd) r = fmaf(pf[dd], hw1[dd * 32 + j], r);
    r = fmaxf(r, 0.f);
    float t = r * hw2[j];
    t += __shfl_xor(t, 1); t += __shfl_xor(t, 2); t += __shfl_xor(t, 4);
    t += __shfl_xor(t, 8); t += __shfl_xor(t, 16);
    if (lane == 0) out[elem] = tanhf(t + hb2[0]);
  }
}

extern "C" void kernel_launch(void* const* d_in, const int* in_sizes, int n_in,
                              void* d_out, int out_size, void* d_ws, size_t ws_size,
                              hipStream_t stream) {
  (void)in_sizes; (void)n_in; (void)ws_size; (void)out_size;
  const float* x    = (const float*)d_in[0];
  const float* w_in = (const float*)d_in[1];
  const float* b_in = (const float*)d_in[2];
  const float* pos  = (const float*)d_in[3];
  const float* wq   = (const float*)d_in[4];
  const float* wk   = (const float*)d_in[5];
  const float* wv   = (const float*)d_in[6];
  const float* wo   = (const float*)d_in[7];
  const float* bo   = (const float*)d_in[8];
  const float* g1   = (const float*)d_in[9];
  const float* be1  = (const float*)d_in[10];
  const float* g2   = (const float*)d_in[11];
  const float* be2  = (const float*)d_in[12];
  const float* w1   = (const float*)d_in[13];
  const float* b1   = (const float*)d_in[14];
  const float* w2   = (const float*)d_in[15];
  const float* b2   = (const float*)d_in[16];
  const float* hw1  = (const float*)d_in[17];
  const float* hb1  = (const float*)d_in[18];
  const float* hw2  = (const float*)d_in[19];
  const float* hb2  = (const float*)d_in[20];
  float* out = (float*)d_out;

  _Float16* wsf = (_Float16*)d_ws;
  float* pbf = (float*)((char*)d_ws + PB_OFF);

  hipLaunchKernelGGL(prep_kernel, dim3(35), dim3(256), 0, stream,
                     w_in, b_in, pos, wq, wk, wv, wo, w1, w2, wsf, pbf);
  hipLaunchKernelGGL(tlob_kernel, dim3(Bsz / NB), dim3(128), 0, stream,
                     x, g1, be1, g2, be2, bo, b1, b2, hw1, hb1, hw2, hb2,
                     (const _Float16*)wsf, (const float*)pbf, out);
}

// Round 4
// 494.711 us; speedup vs baseline: 14.0792x; 1.1411x over previous
//
#include <hip/hip_runtime.h>
#include <cmath>

typedef _Float16 h8_t __attribute__((ext_vector_type(8)));
typedef float f4_t __attribute__((ext_vector_type(4)));

constexpr int Bsz = 32768, S = 32, F = 10, Dm = 64, Ln = 2, DFF = 128;
constexpr int ZP = 72;   // zone pitch (halves)
constexpr int VP = 40;   // vT / pbuf pitch (halves)
constexpr int NB = 2;    // waves (batch elems) per block

constexpr int ZONE_H = S * ZP;                  // 2304 halves
constexpr int VT_H   = Dm * VP;                 // 2560 halves
constexpr int PB_H   = S * VP;                  // 1280 halves
constexpr int SMEM_H = NB * (ZONE_H + VT_H + PB_H);  // 12288 h = 24576 B

constexpr int NFRAG = 4 + Ln * 64;              // 132 weight fragments
constexpr size_t PB_OFF = (size_t)NFRAG * 512 * 2;   // bytes; then pos+bias frags

// ---------------- weight pre-pack kernel ----------------
__global__ __launch_bounds__(256, 2)
void prep_kernel(const float* __restrict__ w_in, const float* __restrict__ b_in,
                 const float* __restrict__ pos,
                 const float* __restrict__ wq, const float* __restrict__ wk,
                 const float* __restrict__ wv, const float* __restrict__ wo,
                 const float* __restrict__ w1, const float* __restrict__ w2,
                 _Float16* __restrict__ wsf, float* __restrict__ pbf) {
  int gid = blockIdx.x * 256 + threadIdx.x;
  int lane = gid & 63;
  int l15 = lane & 15, lk8 = (lane >> 4) << 3;
  if (gid < NFRAG * 64) {
    int frag = gid >> 6;
    float vals[8];
    if (frag < 4) {                       // w_in: nt=frag, kt=0, k>=10 zero
      int n = 16 * frag + l15;
      #pragma unroll
      for (int j = 0; j < 8; ++j) {
        int k = lk8 + j;
        vals[j] = (k < F) ? w_in[k * Dm + n] : 0.f;
      }
    } else {
      int f = frag - 4;
      int layer = f >> 6; f &= 63;
      const float* W; int ncols, n, kbase;
      if (f < 32) {                       // K(0-7) V(8-15) Q(16-23) O(24-31)
        int sub = f >> 3, g = f & 7;
        int nt = g & 3, kt = g >> 2;
        W = ((sub == 0) ? wk : (sub == 1) ? wv : (sub == 2) ? wq : wo) + layer * Dm * Dm;
        ncols = Dm; n = 16 * nt + l15; kbase = kt * 32 + lk8;
      } else if (f < 48) {                // W1: g=kt*8+nt (nt 0..7)
        int g = f - 32, nt = g & 7, kt = g >> 3;
        W = w1 + layer * Dm * DFF; ncols = DFF; n = 16 * nt + l15; kbase = kt * 32 + lk8;
      } else {                            // W2: g=kt*4+nt (kt 0..3)
        int g = f - 48, nt = g & 3, kt = g >> 2;
        W = w2 + layer * DFF * Dm; ncols = Dm; n = 16 * nt + l15; kbase = kt * 32 + lk8;
      }
      #pragma unroll
      for (int j = 0; j < 8; ++j) vals[j] = W[(kbase + j) * ncols + n];
    }
    h8_t o;
    #pragma unroll
    for (int j = 0; j < 8; ++j) o[j] = (_Float16)vals[j];
    *(h8_t*)&wsf[(size_t)gid * 8] = o;
  } else if (gid < NFRAG * 64 + 8 * 64) { // pos+b_in in C-frag layout
    int r = gid - NFRAG * 64;
    int pb = r >> 6;
    int mt = pb >> 2, nt = pb & 3;
    int row = 16 * mt + ((lane >> 4) << 2);
    int col = 16 * nt + l15;
    f4_t v;
    #pragma unroll
    for (int q = 0; q < 4; ++q) v[q] = pos[(row + q) * Dm + col] + b_in[col];
    *(f4_t*)&pbf[(size_t)r * 4] = v;
  }
}

// ---------------- forceinline helpers ----------------
__device__ __forceinline__ f4_t mfma16(h8_t a, h8_t b, f4_t c) {
  return __builtin_amdgcn_mfma_f32_16x16x32_f16(a, b, c, 0, 0, 0);
}
// C-layout store into a pitched LDS buffer; col XOR'd with lk8 (bank swizzle).
__device__ __forceinline__ void cstore(_Float16* buf, int pitch, int mt, int col,
                                       f4_t v, float scale, int lk8, int r0b) {
  int c = col ^ lk8;
  int r = 16 * mt + r0b;
  #pragma unroll
  for (int q = 0; q < 4; ++q) buf[(r + q) * pitch + c] = (_Float16)(v[q] * scale);
}
// A/B fragment read from zone: row l15+16*i1, halves (i2*32+lk8)^swzR.
__device__ __forceinline__ h8_t zfrag(const _Float16* zone, int i1, int i2,
                                      int l15, int lk8, int swzR) {
  return *(const h8_t*)&zone[(l15 + 16 * i1) * ZP + ((i2 * 32 + lk8) ^ swzR)];
}
__device__ __forceinline__ h8_t vpfrag(const _Float16* buf, int row,
                                       int lk8, int swzR) {
  return *(const h8_t*)&buf[row * VP + (lk8 ^ swzR)];
}

struct Frag22 { h8_t f[2][2]; };

// LayerNorm over channels; writes hn to zone and returns the 4 A/B fragments.
__device__ __forceinline__ Frag22 doLN(const f4_t (&hacc)[2][4],
                                       const float* __restrict__ g,
                                       const float* __restrict__ be,
                                       _Float16* zone, int l15, int lk8,
                                       int r0b, int swzR) {
  float gv[4], bv[4];
  #pragma unroll
  for (int nt = 0; nt < 4; ++nt) { gv[nt] = g[l15 + 16 * nt]; bv[nt] = be[l15 + 16 * nt]; }
  #pragma unroll
  for (int mt = 0; mt < 2; ++mt) {
    f4_t ps = hacc[mt][0] + hacc[mt][1] + hacc[mt][2] + hacc[mt][3];
    f4_t pq = hacc[mt][0] * hacc[mt][0] + hacc[mt][1] * hacc[mt][1] +
              hacc[mt][2] * hacc[mt][2] + hacc[mt][3] * hacc[mt][3];
    #pragma unroll
    for (int m = 1; m <= 8; m <<= 1) {
      #pragma unroll
      for (int q = 0; q < 4; ++q) {
        ps[q] += __shfl_xor(ps[q], m);
        pq[q] += __shfl_xor(pq[q], m);
      }
    }
    f4_t muv, rsv;
    #pragma unroll
    for (int q = 0; q < 4; ++q) {
      float mu = ps[q] * (1.f / 64.f);
      float var = pq[q] * (1.f / 64.f) - mu * mu;
      muv[q] = mu; rsv[q] = rsqrtf(var + 1e-5f);
    }
    #pragma unroll
    for (int nt = 0; nt < 4; ++nt) {
      int c = (l15 + 16 * nt) ^ lk8;
      int r = 16 * mt + r0b;
      #pragma unroll
      for (int q = 0; q < 4; ++q) {
        float hn = (hacc[mt][nt][q] - muv[q]) * rsv[q] * gv[nt] + bv[nt];
        zone[(r + q) * ZP + c] = (_Float16)hn;
      }
    }
  }
  Frag22 out;
  #pragma unroll
  for (int i1 = 0; i1 < 2; ++i1)
    #pragma unroll
    for (int i2 = 0; i2 < 2; ++i2) out.f[i1][i2] = zfrag(zone, i1, i2, l15, lk8, swzR);
  return out;
}

// ---------------- fused main kernel: 1 wave per batch element ----------------
__global__ __launch_bounds__(128, 3)
void tlob_kernel(const float* __restrict__ x,
                 const float* __restrict__ g1, const float* __restrict__ be1,
                 const float* __restrict__ g2, const float* __restrict__ be2,
                 const float* __restrict__ bo, const float* __restrict__ b1,
                 const float* __restrict__ b2, const float* __restrict__ hw1,
                 const float* __restrict__ hb1, const float* __restrict__ hw2,
                 const float* __restrict__ hb2,
                 const _Float16* __restrict__ wsf, const float* __restrict__ pbf,
                 float* __restrict__ out) {
  __shared__ __align__(16) _Float16 smem[SMEM_H];
  const int tid = threadIdx.x;
  const int lane = tid & 63;
  const int wid = tid >> 6;
  const int elem = blockIdx.x * NB + wid;

  _Float16* zone = smem + wid * ZONE_H;
  _Float16* vT   = smem + NB * ZONE_H + wid * VT_H;
  _Float16* pb   = smem + NB * (ZONE_H + VT_H) + wid * PB_H;

  const int l15 = lane & 15;
  const int G = lane >> 4;
  const int lk8 = G << 3;
  const int r0b = G << 2;
  const int swzR = ((l15 >> 2) & 3) << 3;

  const h8_t* FR = (const h8_t*)wsf;

  f4_t z4; z4[0] = 0.f; z4[1] = 0.f; z4[2] = 0.f; z4[3] = 0.f;
  h8_t hz;
  #pragma unroll
  for (int j = 0; j < 8; ++j) hz[j] = (_Float16)0.f;

  // ---- x fragments straight from global (K padded 10->32) ----
  h8_t xa[2];
  #pragma unroll
  for (int mt = 0; mt < 2; ++mt) {
    const float* xr = x + (size_t)elem * (S * F) + (16 * mt + l15) * F;
    h8_t v = hz;
    #pragma unroll
    for (int j = 0; j < 8; ++j) {
      int f = lk8 + j;
      if (f < F) v[j] = (_Float16)xr[f];
    }
    xa[mt] = v;
  }

  // ---- input projection: h = x@w_in + b_in + pos ----
  f4_t hacc[2][4];
  #pragma unroll
  for (int nt = 0; nt < 4; ++nt) {
    h8_t wb = FR[nt * 64 + lane];
    #pragma unroll
    for (int mt = 0; mt < 2; ++mt) {
      f4_t ini = *(const f4_t*)&pbf[((size_t)(mt * 4 + nt) * 64 + lane) * 4];
      hacc[mt][nt] = mfma16(xa[mt], wb, ini);
    }
  }

  // ---------------- layers ----------------
  #pragma unroll 1
  for (int layer = 0; layer < Ln; ++layer) {
    const int fb = 4 + layer * 64;   // K+0 V+8 Q+16 O+24 W1+32 W2+48

    Frag22 hnf = doLN(hacc, g1 + layer * Dm, be1 + layer * Dm,
                      zone, l15, lk8, r0b, swzR);

    // ---- K projection -> zone -> A-frags (keys as rows) ----
    h8_t kA[2][2];
    #pragma unroll
    for (int nt = 0; nt < 4; ++nt) {
      h8_t w0 = FR[(fb + nt) * 64 + lane], w1f = FR[(fb + 4 + nt) * 64 + lane];
      #pragma unroll
      for (int mt = 0; mt < 2; ++mt) {
        f4_t acc = mfma16(hnf.f[mt][0], w0, z4);
        acc = mfma16(hnf.f[mt][1], w1f, acc);
        cstore(zone, ZP, mt, l15 + 16 * nt, acc, 1.f, lk8, r0b);
      }
    }
    #pragma unroll
    for (int i1 = 0; i1 < 2; ++i1)
      #pragma unroll
      for (int i2 = 0; i2 < 2; ++i2) kA[i1][i2] = zfrag(zone, i1, i2, l15, lk8, swzR);

    // ---- vT = Wv^T @ hn^T -> vT LDS (rows = channels, cols = keys) ----
    #pragma unroll
    for (int mtd = 0; mtd < 4; ++mtd) {
      h8_t a0 = FR[(fb + 8 + mtd) * 64 + lane], a1 = FR[(fb + 12 + mtd) * 64 + lane];
      #pragma unroll
      for (int nts = 0; nts < 2; ++nts) {
        f4_t acc = mfma16(a0, hnf.f[nts][0], z4);
        acc = mfma16(a1, hnf.f[nts][1], acc);
        cstore(vT, VP, mtd, l15 + 16 * nts, acc, 1.f, lk8, r0b);
      }
    }

    // ---- Q projection (x0.25) -> zone (overwrites hn; hnf regs hold it) ----
    #pragma unroll
    for (int nt = 0; nt < 4; ++nt) {
      h8_t w0 = FR[(fb + 16 + nt) * 64 + lane], w1f = FR[(fb + 20 + nt) * 64 + lane];
      #pragma unroll
      for (int mt = 0; mt < 2; ++mt) {
        f4_t acc = mfma16(hnf.f[mt][0], w0, z4);
        acc = mfma16(hnf.f[mt][1], w1f, acc);
        cstore(zone, ZP, mt, l15 + 16 * nt, acc, 0.25f, lk8, r0b);
      }
    }

    // ---- attention per head-pair; ctx overwrites the pair's q columns ----
    #pragma unroll
    for (int kt = 0; kt < 2; ++kt) {
      h8_t qp0 = zfrag(zone, 0, kt, l15, lk8, swzR);
      h8_t qp1 = zfrag(zone, 1, kt, l15, lk8, swzR);
      #pragma unroll
      for (int sub = 0; sub < 2; ++sub) {
        const int hd = 2 * kt + sub;
        bool keep = (sub == 0) ? (lane < 32) : (lane >= 32);
        h8_t a0 = keep ? kA[0][kt] : hz;
        h8_t a1 = keep ? kA[1][kt] : hz;
        f4_t p[2][2];   // [key-tile][query-tile]
        p[0][0] = mfma16(a0, qp0, z4);
        p[0][1] = mfma16(a0, qp1, z4);
        p[1][0] = mfma16(a1, qp0, z4);
        p[1][1] = mfma16(a1, qp1, z4);
        #pragma unroll
        for (int nq = 0; nq < 2; ++nq) {
          #pragma unroll
          for (int mk = 0; mk < 2; ++mk)
            #pragma unroll
            for (int q = 0; q < 4; ++q) p[mk][nq][q] = __expf(p[mk][nq][q]);
          f4_t s4 = p[0][nq] + p[1][nq];
          float sm = s4[0] + s4[1] + s4[2] + s4[3];
          sm += __shfl_xor(sm, 16);
          sm += __shfl_xor(sm, 32);
          float inv = __builtin_amdgcn_rcpf(sm);
          #pragma unroll
          for (int mk = 0; mk < 2; ++mk)
            #pragma unroll
            for (int q = 0; q < 4; ++q) p[mk][nq][q] *= inv;
        }
        // P^T scatter into pb: pb[query][key]
        #pragma unroll
        for (int nq = 0; nq < 2; ++nq)
          #pragma unroll
          for (int mk = 0; mk < 2; ++mk)
            #pragma unroll
            for (int q = 0; q < 4; ++q)
              pb[(16 * nq + l15) * VP + ((16 * mk + r0b + q) ^ swzR)] =
                  (_Float16)p[mk][nq][q];
        h8_t pA0 = vpfrag(pb, l15, lk8, swzR);
        h8_t pA1 = vpfrag(pb, l15 + 16, lk8, swzR);
        h8_t vB = vpfrag(vT, hd * 16 + l15, lk8, swzR);
        f4_t c0 = mfma16(pA0, vB, z4);
        f4_t c1 = mfma16(pA1, vB, z4);
        cstore(zone, ZP, 0, l15 + 16 * hd, c0, 1.f, lk8, r0b);
        cstore(zone, ZP, 1, l15 + 16 * hd, c1, 1.f, lk8, r0b);
      }
    }

    // ---- O projection with residual C-in ----
    {
      h8_t ca[2][2];
      #pragma unroll
      for (int i1 = 0; i1 < 2; ++i1)
        #pragma unroll
        for (int i2 = 0; i2 < 2; ++i2) ca[i1][i2] = zfrag(zone, i1, i2, l15, lk8, swzR);
      #pragma unroll
      for (int nt = 0; nt < 4; ++nt) {
        h8_t w0 = FR[(fb + 24 + nt) * 64 + lane], w1f = FR[(fb + 28 + nt) * 64 + lane];
        float bov = bo[layer * Dm + l15 + 16 * nt];
        #pragma unroll
        for (int mt = 0; mt < 2; ++mt) {
          f4_t acc = mfma16(ca[mt][0], w0, hacc[mt][nt]);
          acc = mfma16(ca[mt][1], w1f, acc);
          #pragma unroll
          for (int q = 0; q < 4; ++q) hacc[mt][nt][q] = acc[q] + bov;
        }
      }
    }

    // ---- FFN: LN2, two K=64 halves, accumulate into hacc ----
    Frag22 hn2f = doLN(hacc, g2 + layer * Dm, be2 + layer * Dm,
                       zone, l15, lk8, r0b, swzR);
    #pragma unroll 1
    for (int hf = 0; hf < 2; ++hf) {
      #pragma unroll
      for (int ntl = 0; ntl < 4; ++ntl) {
        int ntg = hf * 4 + ntl;
        h8_t w0 = FR[(fb + 32 + ntg) * 64 + lane];
        h8_t w1f = FR[(fb + 40 + ntg) * 64 + lane];
        float b1v = b1[layer * DFF + hf * 64 + l15 + 16 * ntl];
        f4_t bb; bb[0] = b1v; bb[1] = b1v; bb[2] = b1v; bb[3] = b1v;
        #pragma unroll
        for (int mt = 0; mt < 2; ++mt) {
          f4_t acc = mfma16(hn2f.f[mt][0], w0, bb);
          acc = mfma16(hn2f.f[mt][1], w1f, acc);
          #pragma unroll
          for (int q = 0; q < 4; ++q) acc[q] = fmaxf(acc[q], 0.f);
          cstore(zone, ZP, mt, l15 + 16 * ntl, acc, 1.f, lk8, r0b);
        }
      }
      h8_t rf[2][2];
      #pragma unroll
      for (int i1 = 0; i1 < 2; ++i1)
        #pragma unroll
        for (int i2 = 0; i2 < 2; ++i2) rf[i1][i2] = zfrag(zone, i1, i2, l15, lk8, swzR);
      #pragma unroll
      for (int nt = 0; nt < 4; ++nt) {
        h8_t w0 = FR[(fb + 48 + (hf * 2 + 0) * 4 + nt) * 64 + lane];
        h8_t w1f = FR[(fb + 48 + (hf * 2 + 1) * 4 + nt) * 64 + lane];
        #pragma unroll
        for (int mt = 0; mt < 2; ++mt) {
          f4_t acc = mfma16(rf[mt][0], w0, hacc[mt][nt]);
          hacc[mt][nt] = mfma16(rf[mt][1], w1f, acc);
        }
      }
    }
    #pragma unroll
    for (int mt = 0; mt < 2; ++mt)
      #pragma unroll
      for (int nt = 0; nt < 4; ++nt) {
        float b2v = b2[layer * Dm + l15 + 16 * nt];
        #pragma unroll
        for (int q = 0; q < 4; ++q) hacc[mt][nt][q] += b2v;
      }
  }

  // ---------------- head: mean-pool -> 64x32 relu MLP -> tanh ----------------
  {
    float* pf = (float*)zone;
    #pragma unroll
    for (int nt = 0; nt < 4; ++nt) {
      float s = 0.f;
      #pragma unroll
      for (int mt = 0; mt < 2; ++mt)
        #pragma unroll
        for (int q = 0; q < 4; ++q) s += hacc[mt][nt][q];
      s += __shfl_xor(s, 16);
      s += __shfl_xor(s, 32);
      pf[l15 + 16 * nt] = s * (1.f / 32.f);
    }
    int j = lane & 31;
    float r = hb1[j];
    #pragma unroll
    for (int dd = 0; dd < 64; ++dd) r = fmaf(pf[dd], hw1[dd * 32 + j], r);
    r = fmaxf(r, 0.f);
    float t = r * hw2[j];
    t += __shfl_xor(t, 1); t += __shfl_xor(t, 2); t += __shfl_xor(t, 4);
    t += __shfl_xor(t, 8); t += __shfl_xor(t, 16);
    if (lane == 0) out[elem] = tanhf(t + hb2[0]);
  }
}

extern "C" void kernel_launch(void* const* d_in, const int* in_sizes, int n_in,
                              void* d_out, int out_size, void* d_ws, size_t ws_size,
                              hipStream_t stream) {
  (void)in_sizes; (void)n_in; (void)ws_size; (void)out_size;
  const float* x    = (const float*)d_in[0];
  const float* w_in = (const float*)d_in[1];
  const float* b_in = (const float*)d_in[2];
  const float* pos  = (const float*)d_in[3];
  const float* wq   = (const float*)d_in[4];
  const float* wk   = (const float*)d_in[5];
  const float* wv   = (const float*)d_in[6];
  const float* wo   = (const float*)d_in[7];
  const float* bo   = (const float*)d_in[8];
  const float* g1   = (const float*)d_in[9];
  const float* be1  = (const float*)d_in[10];
  const float* g2   = (const float*)d_in[11];
  const float* be2  = (const float*)d_in[12];
  const float* w1   = (const float*)d_in[13];
  const float* b1   = (const float*)d_in[14];
  const float* w2   = (const float*)d_in[15];
  const float* b2   = (const float*)d_in[16];
  const float* hw1  = (const float*)d_in[17];
  const float* hb1  = (const float*)d_in[18];
  const float* hw2  = (const float*)d_in[19];
  const float* hb2  = (const float*)d_in[20];
  float* out = (float*)d_out;

  _Float16* wsf = (_Float16*)d_ws;
  float* pbf = (float*)((char*)d_ws + PB_OFF);

  hipLaunchKernelGGL(prep_kernel, dim3(35), dim3(256), 0, stream,
                     w_in, b_in, pos, wq, wk, wv, wo, w1, w2, wsf, pbf);
  hipLaunchKernelGGL(tlob_kernel, dim3(Bsz / NB), dim3(128), 0, stream,
                     x, g1, be1, g2, be2, bo, b1, b2, hw1, hb1, hw2, hb2,
                     (const _Float16*)wsf, (const float*)pbf, out);
}

// Round 5
// 484.858 us; speedup vs baseline: 14.3653x; 1.0203x over previous
//
#include <hip/hip_runtime.h>
#include <cmath>

typedef _Float16 h8_t __attribute__((ext_vector_type(8)));
typedef float f4_t __attribute__((ext_vector_type(4)));
typedef unsigned int u32x4 __attribute__((ext_vector_type(4)));

constexpr int Bsz = 32768, S = 32, F = 10, Dm = 64, Ln = 2, DFF = 128;
constexpr int ZP = 72;   // zone pitch (halves)
constexpr int VP = 40;   // vT pitch (halves)
constexpr int NB = 2;    // waves (batch elems) per block

constexpr int ZONE_H = S * ZP;                  // 2304 halves
constexpr int VT_H   = Dm * VP;                 // 2560 halves
constexpr int SMEM_H = NB * (ZONE_H + VT_H);    // 9728 h = 19456 B

constexpr int NFRAG = 4 + Ln * 64;              // 132 weight fragments
constexpr size_t PB_OFF = (size_t)NFRAG * 512 * 2;   // bytes; then pos+bias frags

// ---------------- weight pre-pack kernel ----------------
__global__ __launch_bounds__(256, 2)
void prep_kernel(const float* __restrict__ w_in, const float* __restrict__ b_in,
                 const float* __restrict__ pos,
                 const float* __restrict__ wq, const float* __restrict__ wk,
                 const float* __restrict__ wv, const float* __restrict__ wo,
                 const float* __restrict__ w1, const float* __restrict__ w2,
                 _Float16* __restrict__ wsf, float* __restrict__ pbf) {
  int gid = blockIdx.x * 256 + threadIdx.x;
  int lane = gid & 63;
  int l15 = lane & 15, lk8 = (lane >> 4) << 3;
  if (gid < NFRAG * 64) {
    int frag = gid >> 6;
    float vals[8];
    if (frag < 4) {                       // w_in: nt=frag, kt=0, k>=10 zero
      int n = 16 * frag + l15;
      #pragma unroll
      for (int j = 0; j < 8; ++j) {
        int k = lk8 + j;
        vals[j] = (k < F) ? w_in[k * Dm + n] : 0.f;
      }
    } else {
      int f = frag - 4;
      int layer = f >> 6; f &= 63;
      const float* W; int ncols, n, kbase;
      if (f < 32) {                       // K(0-7) V(8-15) Q(16-23) O(24-31)
        int sub = f >> 3, g = f & 7;
        int nt = g & 3, kt = g >> 2;
        W = ((sub == 0) ? wk : (sub == 1) ? wv : (sub == 2) ? wq : wo) + layer * Dm * Dm;
        ncols = Dm; n = 16 * nt + l15; kbase = kt * 32 + lk8;
      } else if (f < 48) {                // W1: g=kt*8+nt (nt 0..7)
        int g = f - 32, nt = g & 7, kt = g >> 3;
        W = w1 + layer * Dm * DFF; ncols = DFF; n = 16 * nt + l15; kbase = kt * 32 + lk8;
      } else {                            // W2: g=kt*4+nt (kt 0..3)
        int g = f - 48, nt = g & 3, kt = g >> 2;
        W = w2 + layer * DFF * Dm; ncols = Dm; n = 16 * nt + l15; kbase = kt * 32 + lk8;
      }
      #pragma unroll
      for (int j = 0; j < 8; ++j) vals[j] = W[(kbase + j) * ncols + n];
    }
    h8_t o;
    #pragma unroll
    for (int j = 0; j < 8; ++j) o[j] = (_Float16)vals[j];
    *(h8_t*)&wsf[(size_t)gid * 8] = o;
  } else if (gid < NFRAG * 64 + 8 * 64) { // pos+b_in in C-frag layout
    int r = gid - NFRAG * 64;
    int pb = r >> 6;
    int mt = pb >> 2, nt = pb & 3;
    int row = 16 * mt + ((lane >> 4) << 2);
    int col = 16 * nt + l15;
    f4_t v;
    #pragma unroll
    for (int q = 0; q < 4; ++q) v[q] = pos[(row + q) * Dm + col] + b_in[col];
    *(f4_t*)&pbf[(size_t)r * 4] = v;
  }
}

// ---------------- forceinline helpers ----------------
__device__ __forceinline__ f4_t mfma16(h8_t a, h8_t b, f4_t c) {
  return __builtin_amdgcn_mfma_f32_16x16x32_f16(a, b, c, 0, 0, 0);
}
// C-layout store into a pitched LDS buffer; col XOR'd with lk8 (bank swizzle).
__device__ __forceinline__ void cstore(_Float16* buf, int pitch, int mt, int col,
                                       f4_t v, float scale, int lk8, int r0b) {
  int c = col ^ lk8;
  int r = 16 * mt + r0b;
  #pragma unroll
  for (int q = 0; q < 4; ++q) buf[(r + q) * pitch + c] = (_Float16)(v[q] * scale);
}
// A/B fragment read from zone: row l15+16*i1, halves (i2*32+lk8)^swzR.
__device__ __forceinline__ h8_t zfrag(const _Float16* zone, int i1, int i2,
                                      int l15, int lk8, int swzR) {
  return *(const h8_t*)&zone[(l15 + 16 * i1) * ZP + ((i2 * 32 + lk8) ^ swzR)];
}
__device__ __forceinline__ h8_t vpfrag(const _Float16* buf, int row,
                                       int lk8, int swzR) {
  return *(const h8_t*)&buf[row * VP + (lk8 ^ swzR)];
}

struct Frag22 { h8_t f[2][2]; };

// LayerNorm over channels; writes hn to zone and returns the 4 A/B fragments.
__device__ __forceinline__ Frag22 doLN(const f4_t (&hacc)[2][4],
                                       const float* __restrict__ g,
                                       const float* __restrict__ be,
                                       _Float16* zone, int l15, int lk8,
                                       int r0b, int swzR) {
  float gv[4], bv[4];
  #pragma unroll
  for (int nt = 0; nt < 4; ++nt) { gv[nt] = g[l15 + 16 * nt]; bv[nt] = be[l15 + 16 * nt]; }
  #pragma unroll
  for (int mt = 0; mt < 2; ++mt) {
    f4_t ps = hacc[mt][0] + hacc[mt][1] + hacc[mt][2] + hacc[mt][3];
    f4_t pq = hacc[mt][0] * hacc[mt][0] + hacc[mt][1] * hacc[mt][1] +
              hacc[mt][2] * hacc[mt][2] + hacc[mt][3] * hacc[mt][3];
    #pragma unroll
    for (int m = 1; m <= 8; m <<= 1) {
      #pragma unroll
      for (int q = 0; q < 4; ++q) {
        ps[q] += __shfl_xor(ps[q], m);
        pq[q] += __shfl_xor(pq[q], m);
      }
    }
    f4_t muv, rsv;
    #pragma unroll
    for (int q = 0; q < 4; ++q) {
      float mu = ps[q] * (1.f / 64.f);
      float var = pq[q] * (1.f / 64.f) - mu * mu;
      muv[q] = mu; rsv[q] = rsqrtf(var + 1e-5f);
    }
    #pragma unroll
    for (int nt = 0; nt < 4; ++nt) {
      int c = (l15 + 16 * nt) ^ lk8;
      int r = 16 * mt + r0b;
      #pragma unroll
      for (int q = 0; q < 4; ++q) {
        float hn = (hacc[mt][nt][q] - muv[q]) * rsv[q] * gv[nt] + bv[nt];
        zone[(r + q) * ZP + c] = (_Float16)hn;
      }
    }
  }
  Frag22 out;
  #pragma unroll
  for (int i1 = 0; i1 < 2; ++i1)
    #pragma unroll
    for (int i2 = 0; i2 < 2; ++i2) out.f[i1][i2] = zfrag(zone, i1, i2, l15, lk8, swzR);
  return out;
}

// ---------------- fused main kernel: 1 wave per batch element ----------------
__global__ __launch_bounds__(128, 3)
void tlob_kernel(const float* __restrict__ x,
                 const float* __restrict__ g1, const float* __restrict__ be1,
                 const float* __restrict__ g2, const float* __restrict__ be2,
                 const float* __restrict__ bo, const float* __restrict__ b1,
                 const float* __restrict__ b2, const float* __restrict__ hw1,
                 const float* __restrict__ hb1, const float* __restrict__ hw2,
                 const float* __restrict__ hb2,
                 const _Float16* __restrict__ wsf, const float* __restrict__ pbf,
                 float* __restrict__ out) {
  __shared__ __align__(16) _Float16 smem[SMEM_H];
  const int tid = threadIdx.x;
  const int lane = tid & 63;
  const int wid = tid >> 6;
  const int elem = blockIdx.x * NB + wid;

  _Float16* zone = smem + wid * ZONE_H;
  _Float16* vT   = smem + NB * ZONE_H + wid * VT_H;

  const int l15 = lane & 15;
  const int G = lane >> 4;
  const int lk8 = G << 3;
  const int r0b = G << 2;
  const int swzR = ((l15 >> 2) & 3) << 3;
  const bool hiMk = (lane >= 32);                 // selects mk=1 chunks in repack
  const int srcA = (((2 * G) & 3) << 4) + l15;    // repack source lanes
  const int srcB = (((2 * G + 1) & 3) << 4) + l15;

  const h8_t* FR = (const h8_t*)wsf;

  f4_t z4; z4[0] = 0.f; z4[1] = 0.f; z4[2] = 0.f; z4[3] = 0.f;
  h8_t hz;
  #pragma unroll
  for (int j = 0; j < 8; ++j) hz[j] = (_Float16)0.f;

  // ---- x fragments straight from global (K padded 10->32) ----
  h8_t xa[2];
  #pragma unroll
  for (int mt = 0; mt < 2; ++mt) {
    const float* xr = x + (size_t)elem * (S * F) + (16 * mt + l15) * F;
    h8_t v = hz;
    #pragma unroll
    for (int j = 0; j < 8; ++j) {
      int f = lk8 + j;
      if (f < F) v[j] = (_Float16)xr[f];
    }
    xa[mt] = v;
  }

  // ---- input projection: h = x@w_in + b_in + pos ----
  f4_t hacc[2][4];
  #pragma unroll
  for (int nt = 0; nt < 4; ++nt) {
    h8_t wb = FR[nt * 64 + lane];
    #pragma unroll
    for (int mt = 0; mt < 2; ++mt) {
      f4_t ini = *(const f4_t*)&pbf[((size_t)(mt * 4 + nt) * 64 + lane) * 4];
      hacc[mt][nt] = mfma16(xa[mt], wb, ini);
    }
  }

  // ---------------- layers ----------------
  #pragma unroll 1
  for (int layer = 0; layer < Ln; ++layer) {
    const int fb = 4 + layer * 64;   // K+0 V+8 Q+16 O+24 W1+32 W2+48

    Frag22 hnf = doLN(hacc, g1 + layer * Dm, be1 + layer * Dm,
                      zone, l15, lk8, r0b, swzR);

    // ---- K projection -> zone -> A-frags (keys as rows) ----
    h8_t kA[2][2];
    #pragma unroll
    for (int nt = 0; nt < 4; ++nt) {
      h8_t w0 = FR[(fb + nt) * 64 + lane], w1f = FR[(fb + 4 + nt) * 64 + lane];
      #pragma unroll
      for (int mt = 0; mt < 2; ++mt) {
        f4_t acc = mfma16(hnf.f[mt][0], w0, z4);
        acc = mfma16(hnf.f[mt][1], w1f, acc);
        cstore(zone, ZP, mt, l15 + 16 * nt, acc, 1.f, lk8, r0b);
      }
    }
    #pragma unroll
    for (int i1 = 0; i1 < 2; ++i1)
      #pragma unroll
      for (int i2 = 0; i2 < 2; ++i2) kA[i1][i2] = zfrag(zone, i1, i2, l15, lk8, swzR);

    // ---- vT = Wv^T @ hn^T -> vT LDS (rows = channels, cols = keys) ----
    #pragma unroll
    for (int mtd = 0; mtd < 4; ++mtd) {
      h8_t a0 = FR[(fb + 8 + mtd) * 64 + lane], a1 = FR[(fb + 12 + mtd) * 64 + lane];
      #pragma unroll
      for (int nts = 0; nts < 2; ++nts) {
        f4_t acc = mfma16(a0, hnf.f[nts][0], z4);
        acc = mfma16(a1, hnf.f[nts][1], acc);
        cstore(vT, VP, mtd, l15 + 16 * nts, acc, 1.f, lk8, r0b);
      }
    }

    // ---- Q projection (x0.25) -> zone (overwrites hn; hnf regs hold it) ----
    #pragma unroll
    for (int nt = 0; nt < 4; ++nt) {
      h8_t w0 = FR[(fb + 16 + nt) * 64 + lane], w1f = FR[(fb + 20 + nt) * 64 + lane];
      #pragma unroll
      for (int mt = 0; mt < 2; ++mt) {
        f4_t acc = mfma16(hnf.f[mt][0], w0, z4);
        acc = mfma16(hnf.f[mt][1], w1f, acc);
        cstore(zone, ZP, mt, l15 + 16 * nt, acc, 0.25f, lk8, r0b);
      }
    }

    // ---- attention: all q frags up front; ctx overwrites q columns ----
    h8_t qp[2][2];   // [nq][kt]
    #pragma unroll
    for (int nq = 0; nq < 2; ++nq)
      #pragma unroll
      for (int kt = 0; kt < 2; ++kt) qp[nq][kt] = zfrag(zone, nq, kt, l15, lk8, swzR);

    #pragma unroll
    for (int kt = 0; kt < 2; ++kt) {
      #pragma unroll
      for (int sub = 0; sub < 2; ++sub) {
        const int hd = 2 * kt + sub;
        bool keep = (sub == 0) ? (lane < 32) : (lane >= 32);
        h8_t a0 = keep ? kA[0][kt] : hz;
        h8_t a1 = keep ? kA[1][kt] : hz;
        // vB early: ds_read overlaps the softmax VALU chain
        h8_t vB = vpfrag(vT, hd * 16 + l15, lk8, swzR);
        f4_t p[2][2];   // [key-tile mk][query-tile nq]
        p[0][0] = mfma16(a0, qp[0][kt], z4);
        p[0][1] = mfma16(a0, qp[1][kt], z4);
        p[1][0] = mfma16(a1, qp[0][kt], z4);
        p[1][1] = mfma16(a1, qp[1][kt], z4);
        h8_t pA[2];
        #pragma unroll
        for (int nq = 0; nq < 2; ++nq) {
          #pragma unroll
          for (int mk = 0; mk < 2; ++mk)
            #pragma unroll
            for (int q = 0; q < 4; ++q) p[mk][nq][q] = __expf(p[mk][nq][q]);
          f4_t s4 = p[0][nq] + p[1][nq];
          float sm = s4[0] + s4[1] + s4[2] + s4[3];
          sm += __shfl_xor(sm, 16);
          sm += __shfl_xor(sm, 32);
          float inv = __builtin_amdgcn_rcpf(sm);
          // pack P (normalized) to fp16 pairs: c0,c1 = mk0 keys {4G..4G+3};
          // c2,c3 = mk1. Then 4-group transpose to A-frag key order 8G..8G+7.
          unsigned int c0 = __builtin_bit_cast(unsigned int,
              __builtin_amdgcn_cvt_pkrtz(p[0][nq][0] * inv, p[0][nq][1] * inv));
          unsigned int c1 = __builtin_bit_cast(unsigned int,
              __builtin_amdgcn_cvt_pkrtz(p[0][nq][2] * inv, p[0][nq][3] * inv));
          unsigned int c2 = __builtin_bit_cast(unsigned int,
              __builtin_amdgcn_cvt_pkrtz(p[1][nq][0] * inv, p[1][nq][1] * inv));
          unsigned int c3 = __builtin_bit_cast(unsigned int,
              __builtin_amdgcn_cvt_pkrtz(p[1][nq][2] * inv, p[1][nq][3] * inv));
          unsigned int m00 = __shfl(c0, srcA), m01 = __shfl(c1, srcA);
          unsigned int m10 = __shfl(c2, srcA), m11 = __shfl(c3, srcA);
          unsigned int n00 = __shfl(c0, srcB), n01 = __shfl(c1, srcB);
          unsigned int n10 = __shfl(c2, srcB), n11 = __shfl(c3, srcB);
          u32x4 d;
          d[0] = hiMk ? m10 : m00;
          d[1] = hiMk ? m11 : m01;
          d[2] = hiMk ? n10 : n00;
          d[3] = hiMk ? n11 : n01;
          pA[nq] = __builtin_bit_cast(h8_t, d);
        }
        f4_t c0x = mfma16(pA[0], vB, z4);
        f4_t c1x = mfma16(pA[1], vB, z4);
        cstore(zone, ZP, 0, l15 + 16 * hd, c0x, 1.f, lk8, r0b);
        cstore(zone, ZP, 1, l15 + 16 * hd, c1x, 1.f, lk8, r0b);
      }
    }

    // ---- O projection with residual C-in ----
    {
      h8_t ca[2][2];
      #pragma unroll
      for (int i1 = 0; i1 < 2; ++i1)
        #pragma unroll
        for (int i2 = 0; i2 < 2; ++i2) ca[i1][i2] = zfrag(zone, i1, i2, l15, lk8, swzR);
      #pragma unroll
      for (int nt = 0; nt < 4; ++nt) {
        h8_t w0 = FR[(fb + 24 + nt) * 64 + lane], w1f = FR[(fb + 28 + nt) * 64 + lane];
        float bov = bo[layer * Dm + l15 + 16 * nt];
        #pragma unroll
        for (int mt = 0; mt < 2; ++mt) {
          f4_t acc = mfma16(ca[mt][0], w0, hacc[mt][nt]);
          acc = mfma16(ca[mt][1], w1f, acc);
          #pragma unroll
          for (int q = 0; q < 4; ++q) hacc[mt][nt][q] = acc[q] + bov;
        }
      }
    }

    // ---- FFN: LN2, two K=64 halves, accumulate into hacc ----
    Frag22 hn2f = doLN(hacc, g2 + layer * Dm, be2 + layer * Dm,
                       zone, l15, lk8, r0b, swzR);
    #pragma unroll 1
    for (int hf = 0; hf < 2; ++hf) {
      #pragma unroll
      for (int ntl = 0; ntl < 4; ++ntl) {
        int ntg = hf * 4 + ntl;
        h8_t w0 = FR[(fb + 32 + ntg) * 64 + lane];
        h8_t w1f = FR[(fb + 40 + ntg) * 64 + lane];
        float b1v = b1[layer * DFF + hf * 64 + l15 + 16 * ntl];
        f4_t bb; bb[0] = b1v; bb[1] = b1v; bb[2] = b1v; bb[3] = b1v;
        #pragma unroll
        for (int mt = 0; mt < 2; ++mt) {
          f4_t acc = mfma16(hn2f.f[mt][0], w0, bb);
          acc = mfma16(hn2f.f[mt][1], w1f, acc);
          #pragma unroll
          for (int q = 0; q < 4; ++q) acc[q] = fmaxf(acc[q], 0.f);
          cstore(zone, ZP, mt, l15 + 16 * ntl, acc, 1.f, lk8, r0b);
        }
      }
      h8_t rf[2][2];
      #pragma unroll
      for (int i1 = 0; i1 < 2; ++i1)
        #pragma unroll
        for (int i2 = 0; i2 < 2; ++i2) rf[i1][i2] = zfrag(zone, i1, i2, l15, lk8, swzR);
      #pragma unroll
      for (int nt = 0; nt < 4; ++nt) {
        h8_t w0 = FR[(fb + 48 + (hf * 2 + 0) * 4 + nt) * 64 + lane];
        h8_t w1f = FR[(fb + 48 + (hf * 2 + 1) * 4 + nt) * 64 + lane];
        #pragma unroll
        for (int mt = 0; mt < 2; ++mt) {
          f4_t acc = mfma16(rf[mt][0], w0, hacc[mt][nt]);
          hacc[mt][nt] = mfma16(rf[mt][1], w1f, acc);
        }
      }
    }
    #pragma unroll
    for (int mt = 0; mt < 2; ++mt)
      #pragma unroll
      for (int nt = 0; nt < 4; ++nt) {
        float b2v = b2[layer * Dm + l15 + 16 * nt];
        #pragma unroll
        for (int q = 0; q < 4; ++q) hacc[mt][nt][q] += b2v;
      }
  }

  // ---------------- head: mean-pool -> 64x32 relu MLP -> tanh ----------------
  {
    float* pf = (float*)zone;
    #pragma unroll
    for (int nt = 0; nt < 4; ++nt) {
      float s = 0.f;
      #pragma unroll
      for (int mt = 0; mt < 2; ++mt)
        #pragma unroll
        for (int q = 0; q < 4; ++q) s += hacc[mt][nt][q];
      s += __shfl_xor(s, 16);
      s += __shfl_xor(s, 32);
      pf[l15 + 16 * nt] = s * (1.f / 32.f);
    }
    int j = lane & 31;
    float r = hb1[j];
    #pragma unroll
    for (int dd = 0; dd < 64; ++dd) r = fmaf(pf[dd], hw1[dd * 32 + j], r);
    r = fmaxf(r, 0.f);
    float t = r * hw2[j];
    t += __shfl_xor(t, 1); t += __shfl_xor(t, 2); t += __shfl_xor(t, 4);
    t += __shfl_xor(t, 8); t += __shfl_xor(t, 16);
    if (lane == 0) out[elem] = tanhf(t + hb2[0]);
  }
}

extern "C" void kernel_launch(void* const* d_in, const int* in_sizes, int n_in,
                              void* d_out, int out_size, void* d_ws, size_t ws_size,
                              hipStream_t stream) {
  (void)in_sizes; (void)n_in; (void)ws_size; (void)out_size;
  const float* x    = (const float*)d_in[0];
  const float* w_in = (const float*)d_in[1];
  const float* b_in = (const float*)d_in[2];
  const float* pos  = (const float*)d_in[3];
  const float* wq   = (const float*)d_in[4];
  const float* wk   = (const float*)d_in[5];
  const float* wv   = (const float*)d_in[6];
  const float* wo   = (const float*)d_in[7];
  const float* bo   = (const float*)d_in[8];
  const float* g1   = (const float*)d_in[9];
  const float* be1  = (const float*)d_in[10];
  const float* g2   = (const float*)d_in[11];
  const float* be2  = (const float*)d_in[12];
  const float* w1   = (const float*)d_in[13];
  const float* b1   = (const float*)d_in[14];
  const float* w2   = (const float*)d_in[15];
  const float* b2   = (const float*)d_in[16];
  const float* hw1  = (const float*)d_in[17];
  const float* hb1  = (const float*)d_in[18];
  const float* hw2  = (const float*)d_in[19];
  const float* hb2  = (const float*)d_in[20];
  float* out = (float*)d_out;

  _Float16* wsf = (_Float16*)d_ws;
  float* pbf = (float*)((char*)d_ws + PB_OFF);

  hipLaunchKernelGGL(prep_kernel, dim3(35), dim3(256), 0, stream,
                     w_in, b_in, pos, wq, wk, wv, wo, w1, w2, wsf, pbf);
  hipLaunchKernelGGL(tlob_kernel, dim3(Bsz / NB), dim3(128), 0, stream,
                     x, g1, be1, g2, be2, bo, b1, b2, hw1, hb1, hw2, hb2,
                     (const _Float16*)wsf, (const float*)pbf, out);
}

// Round 8
// 452.450 us; speedup vs baseline: 15.3943x; 1.0716x over previous
//
#include <hip/hip_runtime.h>
#include <cmath>

typedef _Float16 h8_t __attribute__((ext_vector_type(8)));
typedef _Float16 h2_t __attribute__((ext_vector_type(2)));
typedef float f4_t __attribute__((ext_vector_type(4)));
typedef unsigned int u32x4 __attribute__((ext_vector_type(4)));

constexpr int Bsz = 32768, S = 32, F = 10, Dm = 64, Ln = 2, DFF = 128;
constexpr int NB = 4;                            // waves per block

constexpr int NFRAG = 4 + Ln * 64;               // 132 weight fragments
constexpr size_t PBF_OFF = (size_t)NFRAG * 512 * 2;      // wsf bytes
constexpr size_t CPK_OFF = PBF_OFF + (size_t)8 * 64 * 16; // + pbf (8 f4-frags)

// ---------------- prep: pack weights/params into fragment layouts ----------------
__global__ __launch_bounds__(256, 2)
void prep_kernel(const float* __restrict__ w_in, const float* __restrict__ b_in,
                 const float* __restrict__ pos,
                 const float* __restrict__ wq, const float* __restrict__ wk,
                 const float* __restrict__ wv, const float* __restrict__ wo,
                 const float* __restrict__ bo, const float* __restrict__ g1,
                 const float* __restrict__ be1, const float* __restrict__ g2,
                 const float* __restrict__ be2, const float* __restrict__ w1,
                 const float* __restrict__ b1, const float* __restrict__ w2,
                 const float* __restrict__ b2,
                 _Float16* __restrict__ wsf, float* __restrict__ pbf,
                 float* __restrict__ cpk) {
  int gid = blockIdx.x * 256 + threadIdx.x;
  int lane = gid & 63;
  int l15 = lane & 15, lk8 = (lane >> 4) << 3, r0b = (lane >> 4) << 2;
  if (gid < NFRAG * 64) {
    int frag = gid >> 6;
    float vals[8];
    if (frag < 4) {                       // w_in^T A-frags (K padded 10->32)
      int n = 16 * frag + l15;
      #pragma unroll
      for (int j = 0; j < 8; ++j) {
        int k = lk8 + j;
        vals[j] = (k < F) ? w_in[k * Dm + n] : 0.f;
      }
    } else {
      int f = frag - 4;
      int layer = f >> 6; f &= 63;
      const float* W; int ncols, n, kbase; float scale = 1.f;
      if (f < 32) {                       // K(0-7) V(8-15) Q(16-23) O(24-31)
        int sub = f >> 3, g = f & 7;
        int nt = g & 3, kt = g >> 2;
        W = ((sub == 0) ? wk : (sub == 1) ? wv : (sub == 2) ? wq : wo) + layer * Dm * Dm;
        if (sub == 2) scale = 0.25f;      // fold 1/sqrt(HD) into Wq
        ncols = Dm; n = 16 * nt + l15; kbase = kt * 32 + lk8;
      } else if (f < 48) {                // W1: frag 32 + 8*kt + nt(0..7)
        int g = f - 32, nt = g & 7, kt = g >> 3;
        W = w1 + layer * Dm * DFF; ncols = DFF; n = 16 * nt + l15; kbase = kt * 32 + lk8;
      } else {                            // W2: frag 48 + 4*kt(0..3) + nt
        int g = f - 48, nt = g & 3, kt = g >> 2;
        W = w2 + layer * DFF * Dm; ncols = Dm; n = 16 * nt + l15; kbase = kt * 32 + lk8;
      }
      #pragma unroll
      for (int j = 0; j < 8; ++j) vals[j] = W[(kbase + j) * ncols + n] * scale;
    }
    h8_t o;
    #pragma unroll
    for (int j = 0; j < 8; ++j) o[j] = (_Float16)vals[j];
    *(h8_t*)&wsf[(size_t)gid * 8] = o;
  } else if (gid < NFRAG * 64 + 512) {    // pos+b_in, TRANSPOSED C-frag layout
    int r = gid - NFRAG * 64;             // frag p = ct*2+st
    int p = r >> 6;
    int ct = p >> 1, st = p & 1;
    int seq = l15 + 16 * st;
    f4_t v;
    #pragma unroll
    for (int q = 0; q < 4; ++q) {
      int ch = 16 * ct + r0b + q;
      v[q] = pos[seq * Dm + ch] + b_in[ch];
    }
    *(f4_t*)&pbf[(size_t)r * 4] = v;
  } else if (gid < NFRAG * 64 + 512 + Ln * 32 * 64) {   // per-channel param packs
    int r = gid - NFRAG * 64 - 512;
    int layer = r >> 11;                  // 32 frags * 64 lanes per layer
    int rr = r & 2047;
    int fi = rr >> 6;                     // 0..31
    f4_t v;
    if (fi < 24) {
      int which = fi >> 2, ct = fi & 3;
      const float* arr[6] = {g1, be1, g2, be2, bo, b2};
      const float* src = arr[which] + layer * Dm;
      #pragma unroll
      for (int q = 0; q < 4; ++q) v[q] = src[16 * ct + r0b + q];
    } else {
      int dt = fi - 24;                   // b1 dff tiles 0..7
      const float* src = b1 + layer * DFF;
      #pragma unroll
      for (int q = 0; q < 4; ++q) v[q] = src[16 * dt + r0b + q];
    }
    *(f4_t*)&cpk[((size_t)(layer * 32 + fi) * 64 + lane) * 4] = v;
  }
}

// ---------------- device helpers ----------------
__device__ __forceinline__ f4_t mfma16(h8_t a, h8_t b, f4_t c) {
  return __builtin_amdgcn_mfma_f32_16x16x32_f16(a, b, c, 0, 0, 0);
}
__device__ __forceinline__ unsigned pk2_rne(float a, float b) {
  h2_t r; r[0] = (_Float16)a; r[1] = (_Float16)b;
  return __builtin_bit_cast(unsigned, r);
}
__device__ __forceinline__ unsigned pk2_rtz(float a, float b) {
  return __builtin_bit_cast(unsigned, __builtin_amdgcn_cvt_pkrtz(a, b));
}
// C-layout -> fragment repack. Input: two 16-row C-tiles of M (lo rows 0..15,
// hi rows 16..31, cols in l15). Output: lane ↦ fp16 M[8g+j][l15], the A/B-frag.
template <bool RTZ>
__device__ __forceinline__ h8_t repackF(f4_t lo, f4_t hi, int srcA, int srcB,
                                        bool hiG) {
  unsigned lo01 = RTZ ? pk2_rtz(lo[0], lo[1]) : pk2_rne(lo[0], lo[1]);
  unsigned lo23 = RTZ ? pk2_rtz(lo[2], lo[3]) : pk2_rne(lo[2], lo[3]);
  unsigned hi01 = RTZ ? pk2_rtz(hi[0], hi[1]) : pk2_rne(hi[0], hi[1]);
  unsigned hi23 = RTZ ? pk2_rtz(hi[2], hi[3]) : pk2_rne(hi[2], hi[3]);
  unsigned a0 = __shfl((int)lo01, srcA), a1 = __shfl((int)lo23, srcA);
  unsigned b0 = __shfl((int)hi01, srcA), b1 = __shfl((int)hi23, srcA);
  unsigned c0 = __shfl((int)lo01, srcB), c1 = __shfl((int)lo23, srcB);
  unsigned d0 = __shfl((int)hi01, srcB), d1 = __shfl((int)hi23, srcB);
  u32x4 r;
  r[0] = hiG ? b0 : a0;
  r[1] = hiG ? b1 : a1;
  r[2] = hiG ? d0 : c0;
  r[3] = hiG ? d1 : c1;
  return __builtin_bit_cast(h8_t, r);
}
// LayerNorm over channels of h^T C-frags [ct][st]; emits fragment form.
__device__ __forceinline__ void doLN(const f4_t (&h)[4][2], const f4_t (&gp)[4],
                                     const f4_t (&bp)[4], h8_t (&hF)[2][2],
                                     int srcA, int srcB, bool hiG) {
  #pragma unroll
  for (int st = 0; st < 2; ++st) {
    f4_t s = h[0][st] + h[1][st] + h[2][st] + h[3][st];
    f4_t s2 = h[0][st] * h[0][st] + h[1][st] * h[1][st] +
              h[2][st] * h[2][st] + h[3][st] * h[3][st];
    float sum = s[0] + s[1] + s[2] + s[3];
    float sq  = s2[0] + s2[1] + s2[2] + s2[3];
    sum += __shfl_xor(sum, 16); sum += __shfl_xor(sum, 32);
    sq  += __shfl_xor(sq, 16);  sq  += __shfl_xor(sq, 32);
    float mu = sum * (1.f / 64.f);
    float var = sq * (1.f / 64.f) - mu * mu;
    float rs = rsqrtf(var + 1e-5f);
    f4_t hn[4];
    #pragma unroll
    for (int ct = 0; ct < 4; ++ct) {
      #pragma unroll
      for (int q = 0; q < 4; ++q)
        hn[ct][q] = (h[ct][st][q] - mu) * rs * gp[ct][q] + bp[ct][q];
    }
    hF[0][st] = repackF<false>(hn[0], hn[1], srcA, srcB, hiG);
    hF[1][st] = repackF<false>(hn[2], hn[3], srcA, srcB, hiG);
  }
}

// ---------------- fused main kernel: 1 wave per batch element, no act-LDS ----------------
__global__ __launch_bounds__(256, 3)
void tlob_kernel(const float* __restrict__ x,
                 const float* __restrict__ hw1, const float* __restrict__ hb1,
                 const float* __restrict__ hw2, const float* __restrict__ hb2,
                 const _Float16* __restrict__ wsf, const float* __restrict__ pbf,
                 const float* __restrict__ cpk, float* __restrict__ out) {
  __shared__ float pfs[NB][64];
  const int tid = threadIdx.x, lane = tid & 63, wid = tid >> 6;
  const int elem = blockIdx.x * NB + wid;
  const int l15 = lane & 15, G = lane >> 4;
  const int lk8 = G << 3, r0b = G << 2;
  const int srcA = (((2 * G) & 3) << 4) | l15;
  const int srcB = (((2 * G + 1) & 3) << 4) | l15;
  const bool hiG = (lane >= 32);

  const h8_t* FR = (const h8_t*)wsf;
  const f4_t* PB = (const f4_t*)pbf;
  const f4_t* CP = (const f4_t*)cpk;
  auto ldf = [&](int f) -> h8_t { return FR[f * 64 + lane]; };
  auto ldc = [&](int layer, int fi) -> f4_t { return CP[(layer * 32 + fi) * 64 + lane]; };

  f4_t z4; z4[0] = 0.f; z4[1] = 0.f; z4[2] = 0.f; z4[3] = 0.f;
  h8_t hz;
  #pragma unroll
  for (int j = 0; j < 8; ++j) hz[j] = (_Float16)0.f;

  // ---- x as B-frags of x^T: lane ↦ x[seq l15+16st][f 8G+j] ----
  h8_t xB[2];
  #pragma unroll
  for (int st = 0; st < 2; ++st) {
    const float* xr = x + (size_t)elem * (S * F) + (16 * st + l15) * F;
    h8_t v = hz;
    #pragma unroll
    for (int j = 0; j < 8; ++j) {
      int f = lk8 + j;
      if (f < F) v[j] = (_Float16)xr[f];
    }
    xB[st] = v;
  }

  // ---- input projection: h^T = w_in^T x^T + (pos+b)^T ----
  f4_t hacc[4][2];   // [chan-tile ct][seq-tile st]
  #pragma unroll
  for (int ct = 0; ct < 4; ++ct) {
    h8_t wf = ldf(ct);
    #pragma unroll
    for (int st = 0; st < 2; ++st)
      hacc[ct][st] = mfma16(wf, xB[st], PB[(ct * 2 + st) * 64 + lane]);
  }

  // ---------------- layers ----------------
  #pragma unroll 1
  for (int layer = 0; layer < Ln; ++layer) {
    const int fb = 4 + layer * 64;   // K+0 V+8 Q+16 O+24 W1+32 W2+48

    // ---- LN1 -> hn fragments ----
    f4_t gp[4], bp[4];
    #pragma unroll
    for (int ct = 0; ct < 4; ++ct) { gp[ct] = ldc(layer, ct); bp[ct] = ldc(layer, 4 + ct); }
    h8_t hnF[2][2];
    doLN(hacc, gp, bp, hnF, srcA, srcB, hiG);

    // ---- k^T = Wk^T hn^T -> kF ----
    h8_t kF[2][2];
    {
      f4_t kc[4][2];
      #pragma unroll
      for (int ot = 0; ot < 4; ++ot) {
        h8_t w0 = ldf(fb + ot), w1 = ldf(fb + 4 + ot);
        #pragma unroll
        for (int st = 0; st < 2; ++st)
          kc[ot][st] = mfma16(w1, hnF[1][st], mfma16(w0, hnF[0][st], z4));
      }
      #pragma unroll
      for (int kt = 0; kt < 2; ++kt)
        #pragma unroll
        for (int st = 0; st < 2; ++st)
          kF[kt][st] = repackF<false>(kc[2 * kt][st], kc[2 * kt + 1][st], srcA, srcB, hiG);
    }
    // ---- q^T (0.25 pre-folded) -> qF ----
    h8_t qF[2][2];
    {
      f4_t qc[4][2];
      #pragma unroll
      for (int ot = 0; ot < 4; ++ot) {
        h8_t w0 = ldf(fb + 16 + ot), w1 = ldf(fb + 20 + ot);
        #pragma unroll
        for (int st = 0; st < 2; ++st)
          qc[ot][st] = mfma16(w1, hnF[1][st], mfma16(w0, hnF[0][st], z4));
      }
      #pragma unroll
      for (int kt = 0; kt < 2; ++kt)
        #pragma unroll
        for (int st = 0; st < 2; ++st)
          qF[kt][st] = repackF<false>(qc[2 * kt][st], qc[2 * kt + 1][st], srcA, srcB, hiG);
    }
    // ---- v = hn Wv (row form) -> vB ----
    h8_t vB[4];
    {
      f4_t vc[2][4];
      #pragma unroll
      for (int nt = 0; nt < 4; ++nt) {
        h8_t w0 = ldf(fb + 8 + nt), w1 = ldf(fb + 12 + nt);
        #pragma unroll
        for (int mt = 0; mt < 2; ++mt)
          vc[mt][nt] = mfma16(hnF[1][mt], w1, mfma16(hnF[0][mt], w0, z4));
      }
      #pragma unroll
      for (int nt = 0; nt < 4; ++nt)
        vB[nt] = repackF<false>(vc[0][nt], vc[1][nt], srcA, srcB, hiG);
    }

    // ---- attention: S^T = K Q^T (masked per head), softmax, ctx^T = v^T P^T ----
    f4_t ctx[4][2];   // ctx^T C-frags, [head=ct][st]
    #pragma unroll
    for (int hd = 0; hd < 4; ++hd) {
      const int kt = hd >> 1;
      bool keep = (hd & 1) ? (lane >= 32) : (lane < 32);
      h8_t a0 = keep ? kF[kt][0] : hz;
      h8_t a1 = keep ? kF[kt][1] : hz;
      f4_t p[2][2];   // [k-tile][q-tile]
      #pragma unroll
      for (int sq = 0; sq < 2; ++sq) {
        p[0][sq] = mfma16(a0, qF[kt][sq], z4);
        p[1][sq] = mfma16(a1, qF[kt][sq], z4);
      }
      #pragma unroll
      for (int sq = 0; sq < 2; ++sq) {
        #pragma unroll
        for (int mk = 0; mk < 2; ++mk)
          #pragma unroll
          for (int q = 0; q < 4; ++q) p[mk][sq][q] = __expf(p[mk][sq][q]);
        f4_t t = p[0][sq] + p[1][sq];
        float sm = t[0] + t[1] + t[2] + t[3];
        sm += __shfl_xor(sm, 16);
        sm += __shfl_xor(sm, 32);
        float inv = __builtin_amdgcn_rcpf(sm);
        f4_t plo, phi;
        #pragma unroll
        for (int q = 0; q < 4; ++q) { plo[q] = p[0][sq][q] * inv; phi[q] = p[1][sq][q] * inv; }
        h8_t pF = repackF<true>(plo, phi, srcA, srcB, hiG);
        ctx[hd][sq] = mfma16(vB[hd], pF, z4);
      }
    }

    // ---- O projection (residual C-in) + bo ----
    {
      h8_t cF[2][2];
      #pragma unroll
      for (int st = 0; st < 2; ++st) {
        cF[0][st] = repackF<false>(ctx[0][st], ctx[1][st], srcA, srcB, hiG);
        cF[1][st] = repackF<false>(ctx[2][st], ctx[3][st], srcA, srcB, hiG);
      }
      f4_t bop[4];
      #pragma unroll
      for (int ct = 0; ct < 4; ++ct) bop[ct] = ldc(layer, 16 + ct);
      #pragma unroll
      for (int ot = 0; ot < 4; ++ot) {
        h8_t w0 = ldf(fb + 24 + ot), w1 = ldf(fb + 28 + ot);
        #pragma unroll
        for (int st = 0; st < 2; ++st) {
          f4_t acc = mfma16(w1, cF[1][st], mfma16(w0, cF[0][st], hacc[ot][st]));
          #pragma unroll
          for (int q = 0; q < 4; ++q) hacc[ot][st][q] = acc[q] + bop[ot][q];
        }
      }
    }

    // ---- FFN: LN2, two DFF halves, accumulate into h^T ----
    #pragma unroll
    for (int ct = 0; ct < 4; ++ct) { gp[ct] = ldc(layer, 8 + ct); bp[ct] = ldc(layer, 12 + ct); }
    h8_t h2F[2][2];
    doLN(hacc, gp, bp, h2F, srcA, srcB, hiG);
    #pragma unroll
    for (int half = 0; half < 2; ++half) {
      f4_t a1c[4][2];
      #pragma unroll
      for (int otl = 0; otl < 4; ++otl) {
        int ot = 4 * half + otl;
        h8_t w0 = ldf(fb + 32 + ot), w1 = ldf(fb + 40 + ot);
        f4_t b1p = ldc(layer, 24 + ot);
        #pragma unroll
        for (int st = 0; st < 2; ++st) {
          f4_t acc = mfma16(w1, h2F[1][st], mfma16(w0, h2F[0][st], b1p));
          #pragma unroll
          for (int q = 0; q < 4; ++q) acc[q] = fmaxf(acc[q], 0.f);
          a1c[otl][st] = acc;
        }
      }
      h8_t rF[2][2];
      #pragma unroll
      for (int ktl = 0; ktl < 2; ++ktl)
        #pragma unroll
        for (int st = 0; st < 2; ++st)
          rF[ktl][st] = repackF<false>(a1c[2 * ktl][st], a1c[2 * ktl + 1][st], srcA, srcB, hiG);
      #pragma unroll
      for (int ot = 0; ot < 4; ++ot) {
        h8_t w0 = ldf(fb + 48 + 4 * (2 * half + 0) + ot);
        h8_t w1 = ldf(fb + 48 + 4 * (2 * half + 1) + ot);
        #pragma unroll
        for (int st = 0; st < 2; ++st)
          hacc[ot][st] = mfma16(w1, rF[1][st], mfma16(w0, rF[0][st], hacc[ot][st]));
      }
    }
    {
      f4_t b2p[4];
      #pragma unroll
      for (int ct = 0; ct < 4; ++ct) b2p[ct] = ldc(layer, 20 + ct);
      #pragma unroll
      for (int ct = 0; ct < 4; ++ct)
        #pragma unroll
        for (int st = 0; st < 2; ++st)
          #pragma unroll
          for (int q = 0; q < 4; ++q) hacc[ct][st][q] += b2p[ct][q];
    }
  }

  // ---------------- head: mean-pool -> 64x32 relu MLP -> tanh ----------------
  {
    float* pf = pfs[wid];
    f4_t t[4];
    #pragma unroll
    for (int ct = 0; ct < 4; ++ct) t[ct] = hacc[ct][0] + hacc[ct][1];
    #pragma unroll
    for (int m = 1; m <= 8; m <<= 1) {
      #pragma unroll
      for (int ct = 0; ct < 4; ++ct)
        #pragma unroll
        for (int q = 0; q < 4; ++q) t[ct][q] += __shfl_xor(t[ct][q], m);
    }
    if (l15 == 0) {
      #pragma unroll
      for (int ct = 0; ct < 4; ++ct)
        #pragma unroll
        for (int q = 0; q < 4; ++q)
          pf[16 * ct + r0b + q] = t[ct][q] * (1.f / 32.f);
    }
    int j = lane & 31;
    float r = hb1[j];
    #pragma unroll
    for (int dd = 0; dd < 64; ++dd) r = fmaf(pf[dd], hw1[dd * 32 + j], r);
    r = fmaxf(r, 0.f);
    float tt = r * hw2[j];
    tt += __shfl_xor(tt, 1); tt += __shfl_xor(tt, 2); tt += __shfl_xor(tt, 4);
    tt += __shfl_xor(tt, 8); tt += __shfl_xor(tt, 16);
    if (lane == 0) out[elem] = tanhf(tt + hb2[0]);
  }
}

extern "C" void kernel_launch(void* const* d_in, const int* in_sizes, int n_in,
                              void* d_out, int out_size, void* d_ws, size_t ws_size,
                              hipStream_t stream) {
  (void)in_sizes; (void)n_in; (void)ws_size; (void)out_size;
  const float* x    = (const float*)d_in[0];
  const float* w_in = (const float*)d_in[1];
  const float* b_in = (const float*)d_in[2];
  const float* pos  = (const float*)d_in[3];
  const float* wq   = (const float*)d_in[4];
  const float* wk   = (const float*)d_in[5];
  const float* wv   = (const float*)d_in[6];
  const float* wo   = (const float*)d_in[7];
  const float* bo   = (const float*)d_in[8];
  const float* g1   = (const float*)d_in[9];
  const float* be1  = (const float*)d_in[10];
  const float* g2   = (const float*)d_in[11];
  const float* be2  = (const float*)d_in[12];
  const float* w1   = (const float*)d_in[13];
  const float* b1   = (const float*)d_in[14];
  const float* w2   = (const float*)d_in[15];
  const float* b2   = (const float*)d_in[16];
  const float* hw1  = (const float*)d_in[17];
  const float* hb1  = (const float*)d_in[18];
  const float* hw2  = (const float*)d_in[19];
  const float* hb2  = (const float*)d_in[20];
  float* out = (float*)d_out;

  _Float16* wsf = (_Float16*)d_ws;
  float* pbf = (float*)((char*)d_ws + PBF_OFF);
  float* cpk = (float*)((char*)d_ws + CPK_OFF);

  hipLaunchKernelGGL(prep_kernel, dim3(51), dim3(256), 0, stream,
                     w_in, b_in, pos, wq, wk, wv, wo, bo, g1, be1, g2, be2,
                     w1, b1, w2, b2, wsf, pbf, cpk);
  hipLaunchKernelGGL(tlob_kernel, dim3(Bsz / NB), dim3(256), 0, stream,
                     x, hw1, hb1, hw2, hb2,
                     (const _Float16*)wsf, (const float*)pbf, (const float*)cpk, out);
}